// Round 1
// baseline (8086.698 us; speedup 1.0000x reference)
//
#include <hip/hip_runtime.h>

#define T_N 6000
#define H_N 4000
#define N_N 12000
#define DIM 256
#define NHEAD 8
#define HDIM 32
#define EVOC 64
#define SCALING 0.17677669529663687f  // 32^-0.5

// ---------------------------------------------------------------------------
// GEMM: out[r, j] = (sum_k X[src(r), k] * W[j, k] + b[j]) * scale
// src(r) = idx ? idx[r] : r.  64x64 tile, 256 threads, 4x4 micro-tile.
// ---------------------------------------------------------------------------
__global__ __launch_bounds__(256) void gemm_proj(
    const float* __restrict__ X, const int* __restrict__ idx,
    const float* __restrict__ W, const float* __restrict__ b,
    float* __restrict__ out, int rows, float scale)
{
  __shared__ __align__(16) float As[16][64];
  __shared__ __align__(16) float Bs[16][64];

  const int tid = threadIdx.x;
  const int tx = tid & 15;        // 0..15 -> 4 output cols each
  const int ty = tid >> 4;        // 0..15 -> 4 output rows each
  const int i0 = blockIdx.x * 64;
  const int j0 = blockIdx.y * 64;
  const int lk = tid & 15;        // k within k-tile for staging
  const int lr = tid >> 4;        // row/col group for staging

  float c[4][4];
#pragma unroll
  for (int r = 0; r < 4; r++)
#pragma unroll
    for (int cc = 0; cc < 4; cc++) c[r][cc] = 0.f;

  for (int kt = 0; kt < DIM; kt += 16) {
#pragma unroll
    for (int rr = 0; rr < 4; rr++) {
      const int il = lr + rr * 16;       // 0..63
      const int row = i0 + il;
      float a = 0.f;
      if (row < rows) {
        const int src = idx ? idx[row] : row;
        a = X[src * DIM + kt + lk];
      }
      As[lk][il] = a;
      Bs[lk][il] = W[(j0 + il) * DIM + kt + lk];
    }
    __syncthreads();
#pragma unroll
    for (int kk = 0; kk < 16; kk++) {
      const float4 av = *reinterpret_cast<const float4*>(&As[kk][ty * 4]);
      const float4 bv = *reinterpret_cast<const float4*>(&Bs[kk][tx * 4]);
      const float aa[4] = {av.x, av.y, av.z, av.w};
      const float bb[4] = {bv.x, bv.y, bv.z, bv.w};
#pragma unroll
      for (int r = 0; r < 4; r++)
#pragma unroll
        for (int cc = 0; cc < 4; cc++)
          c[r][cc] = fmaf(aa[r], bb[cc], c[r][cc]);
    }
    __syncthreads();
  }

#pragma unroll
  for (int r = 0; r < 4; r++) {
    const int row = i0 + ty * 4 + r;
    if (row < rows) {
      const int j = j0 + tx * 4;
      float4 o;
      o.x = (c[r][0] + b[j + 0]) * scale;
      o.y = (c[r][1] + b[j + 1]) * scale;
      o.z = (c[r][2] + b[j + 2]) * scale;
      o.w = (c[r][3] + b[j + 3]) * scale;
      *reinterpret_cast<float4*>(&out[row * DIM + j]) = o;
    }
  }
}

// ---------------------------------------------------------------------------
// Fused bipartite attention. One block (4 waves) per tail row t.
// Wave w handles heads 2w, 2w+1. Lanes parallelize over the H_N keys with
// per-lane online softmax; merged via shfl butterfly + LDS column transpose.
// Writes out_tail rows scattered to attn_all[tail_idx[t]].
// ---------------------------------------------------------------------------
__global__ __launch_bounds__(256) void attn_fused(
    const float* __restrict__ Qp, const float* __restrict__ Kp,
    const float* __restrict__ Vp, const int* __restrict__ adj,
    const int* __restrict__ cind, const float* __restrict__ edge_emb,
    const int* __restrict__ tail_idx, float* __restrict__ attn_all)
{
  __shared__ float red[4][64][33];   // padded: +1 breaks bank aliasing

  const int t = blockIdx.x;
  const int tid = threadIdx.x;
  const int wave = tid >> 6;
  const int lane = tid & 63;
  const int h0 = wave * 2;
  const int h1 = h0 + 1;

  // Per-lane copy of this tail row's q for both heads (uniform across lanes).
  float q0[HDIM], q1[HDIM];
#pragma unroll
  for (int j = 0; j < HDIM; j += 4) {
    const float4 a = *reinterpret_cast<const float4*>(&Qp[t * DIM + h0 * HDIM + j]);
    q0[j + 0] = a.x; q0[j + 1] = a.y; q0[j + 2] = a.z; q0[j + 3] = a.w;
    const float4 bqv = *reinterpret_cast<const float4*>(&Qp[t * DIM + h1 * HDIM + j]);
    q1[j + 0] = bqv.x; q1[j + 1] = bqv.y; q1[j + 2] = bqv.z; q1[j + 3] = bqv.w;
  }

  float m0 = -1e30f, l0 = 0.f, m1 = -1e30f, l1 = 0.f;
  float acc0[HDIM], acc1[HDIM];
#pragma unroll
  for (int j = 0; j < HDIM; j++) { acc0[j] = 0.f; acc1[j] = 0.f; }

  const int base = t * H_N;
  for (int s = lane; s < H_N; s += 64) {
    const int a = adj[base + s];
    const int c = cind[base + s];
    const float bias0 = edge_emb[c * NHEAD + h0];
    const float bias1 = edge_emb[c * NHEAD + h1];

    const float* krow = Kp + s * DIM;
    float s0 = 0.f, s1 = 0.f;
#pragma unroll
    for (int j = 0; j < HDIM; j += 4) {
      const float4 k0 = *reinterpret_cast<const float4*>(krow + h0 * HDIM + j);
      s0 = fmaf(q0[j + 0], k0.x, s0);
      s0 = fmaf(q0[j + 1], k0.y, s0);
      s0 = fmaf(q0[j + 2], k0.z, s0);
      s0 = fmaf(q0[j + 3], k0.w, s0);
      const float4 k1 = *reinterpret_cast<const float4*>(krow + h1 * HDIM + j);
      s1 = fmaf(q1[j + 0], k1.x, s1);
      s1 = fmaf(q1[j + 1], k1.y, s1);
      s1 = fmaf(q1[j + 2], k1.z, s1);
      s1 = fmaf(q1[j + 3], k1.w, s1);
    }
    const float mask = a ? 0.f : -1e9f;
    const float sc0 = s0 + bias0 + mask;
    const float sc1 = s1 + bias1 + mask;

    const float* vrow = Vp + s * DIM;
    // head0 online update
    {
      const float mn = fmaxf(m0, sc0);
      const float corr = __expf(m0 - mn);
      const float p = __expf(sc0 - mn);
      l0 = l0 * corr + p;
      m0 = mn;
#pragma unroll
      for (int j = 0; j < HDIM; j += 4) {
        const float4 vv = *reinterpret_cast<const float4*>(vrow + h0 * HDIM + j);
        acc0[j + 0] = fmaf(acc0[j + 0], corr, p * vv.x);
        acc0[j + 1] = fmaf(acc0[j + 1], corr, p * vv.y);
        acc0[j + 2] = fmaf(acc0[j + 2], corr, p * vv.z);
        acc0[j + 3] = fmaf(acc0[j + 3], corr, p * vv.w);
      }
    }
    // head1 online update
    {
      const float mn = fmaxf(m1, sc1);
      const float corr = __expf(m1 - mn);
      const float p = __expf(sc1 - mn);
      l1 = l1 * corr + p;
      m1 = mn;
#pragma unroll
      for (int j = 0; j < HDIM; j += 4) {
        const float4 vv = *reinterpret_cast<const float4*>(vrow + h1 * HDIM + j);
        acc1[j + 0] = fmaf(acc1[j + 0], corr, p * vv.x);
        acc1[j + 1] = fmaf(acc1[j + 1], corr, p * vv.y);
        acc1[j + 2] = fmaf(acc1[j + 2], corr, p * vv.z);
        acc1[j + 3] = fmaf(acc1[j + 3], corr, p * vv.w);
      }
    }
  }

  // Merge (m,l) across the wave -> global M, L (all lanes converge).
  float M0 = m0, L0 = l0, M1 = m1, L1 = l1;
#pragma unroll
  for (int off = 32; off > 0; off >>= 1) {
    const float mo0 = __shfl_xor(M0, off, 64);
    const float lo0 = __shfl_xor(L0, off, 64);
    const float mn0 = fmaxf(M0, mo0);
    L0 = L0 * __expf(M0 - mn0) + lo0 * __expf(mo0 - mn0);
    M0 = mn0;
    const float mo1 = __shfl_xor(M1, off, 64);
    const float lo1 = __shfl_xor(L1, off, 64);
    const float mn1 = fmaxf(M1, mo1);
    L1 = L1 * __expf(M1 - mn1) + lo1 * __expf(mo1 - mn1);
    M1 = mn1;
  }
  const float w0 = __expf(m0 - M0);
  const float w1 = __expf(m1 - M1);

  const int j = lane & 31;
  const int hs = lane >> 5;
  const int row = tail_idx[t];

  // head0: LDS transpose + column sum
#pragma unroll
  for (int jj = 0; jj < HDIM; jj++) red[wave][lane][jj] = acc0[jj] * w0;
  __syncthreads();
  float sum0 = 0.f;
#pragma unroll
  for (int u = 0; u < 32; u++) sum0 += red[wave][hs * 32 + u][j];
  sum0 += __shfl_xor(sum0, 32, 64);
  __syncthreads();

  // head1
#pragma unroll
  for (int jj = 0; jj < HDIM; jj++) red[wave][lane][jj] = acc1[jj] * w1;
  __syncthreads();
  float sum1 = 0.f;
#pragma unroll
  for (int u = 0; u < 32; u++) sum1 += red[wave][hs * 32 + u][j];
  sum1 += __shfl_xor(sum1, 32, 64);

  if (lane < 32) {
    attn_all[row * DIM + h0 * HDIM + j] = sum0 / L0;
    attn_all[row * DIM + h1 * HDIM + j] = sum1 / L1;
  }
}

// ---------------------------------------------------------------------------
// Head rows pass through: attn_all[head_idx[s]] = query[head_idx[s]]
// ---------------------------------------------------------------------------
__global__ __launch_bounds__(64) void copy_head_rows(
    const float* __restrict__ query, const int* __restrict__ head_idx,
    float* __restrict__ attn_all)
{
  const int s = blockIdx.x;
  const int row = head_idx[s];
  const int lane = threadIdx.x;  // 64 lanes, one float4 each (256 floats/row)
  const float4* src = reinterpret_cast<const float4*>(&query[row * DIM]);
  float4* dst = reinterpret_cast<float4*>(&attn_all[row * DIM]);
  dst[lane] = src[lane];
}

// ---------------------------------------------------------------------------
extern "C" void kernel_launch(void* const* d_in, const int* in_sizes, int n_in,
                              void* d_out, int out_size, void* d_ws, size_t ws_size,
                              hipStream_t stream)
{
  const float* query    = (const float*)d_in[0];
  const float* key      = (const float*)d_in[1];
  const float* value    = (const float*)d_in[2];
  const int*   adj      = (const int*)d_in[3];
  const int*   cind     = (const int*)d_in[4];
  const int*   tail_idx = (const int*)d_in[5];
  const int*   head_idx = (const int*)d_in[6];
  const float* Wq = (const float*)d_in[7];
  const float* bq = (const float*)d_in[8];
  const float* Wk = (const float*)d_in[9];
  const float* bk = (const float*)d_in[10];
  const float* Wv = (const float*)d_in[11];
  const float* bv = (const float*)d_in[12];
  const float* Wo = (const float*)d_in[13];
  const float* bo = (const float*)d_in[14];
  const float* edge_emb = (const float*)d_in[15];

  float* out = (float*)d_out;
  float* ws  = (float*)d_ws;

  float* Qp   = ws;                          // T_N * DIM
  float* Kp   = Qp + (size_t)T_N * DIM;      // H_N * DIM
  float* Vp   = Kp + (size_t)H_N * DIM;      // H_N * DIM
  float* attn = Vp + (size_t)H_N * DIM;      // N_N * DIM

  // Rows of attn_all not hit by tail/head scatter must be zero (ws is poisoned).
  hipMemsetAsync(attn, 0, (size_t)N_N * DIM * sizeof(float), stream);

  const dim3 blk(256);
  gemm_proj<<<dim3((T_N + 63) / 64, DIM / 64), blk, 0, stream>>>(
      query, tail_idx, Wq, bq, Qp, T_N, SCALING);
  gemm_proj<<<dim3((H_N + 63) / 64, DIM / 64), blk, 0, stream>>>(
      key, head_idx, Wk, bk, Kp, H_N, 1.f);
  gemm_proj<<<dim3((H_N + 63) / 64, DIM / 64), blk, 0, stream>>>(
      value, head_idx, Wv, bv, Vp, H_N, 1.f);

  attn_fused<<<dim3(T_N), blk, 0, stream>>>(Qp, Kp, Vp, adj, cind, edge_emb,
                                            tail_idx, attn);
  copy_head_rows<<<dim3(H_N), dim3(64), 0, stream>>>(query, head_idx, attn);

  gemm_proj<<<dim3((N_N + 63) / 64, DIM / 64), blk, 0, stream>>>(
      attn, nullptr, Wo, bo, out, N_N, 1.f);
}

// Round 2
// 405.020 us; speedup vs baseline: 19.9662x; 19.9662x over previous
//
#include <hip/hip_runtime.h>
#include <hip/hip_bf16.h>

#define T_N 6000
#define H_N 4000
#define N_N 12000
#define DIM 256
#define NHEAD 8
#define HDIM 32
#define SCALING 0.17677669529663687f  // 32^-0.5

typedef __attribute__((ext_vector_type(8))) short bf16x8;
typedef __attribute__((ext_vector_type(16))) float f32x16;

union BF8U {
  bf16x8 v;
  unsigned int w[4];
  __hip_bfloat16 h[8];
};

static __device__ __forceinline__ unsigned int cvt_pk_bf16(float a, float b) {
  unsigned int r;
  asm("v_cvt_pk_bf16_f32 %0, %1, %2" : "=v"(r) : "v"(a), "v"(b));
  return r;
}

// ---------------------------------------------------------------------------
// GEMM: out[r, j] = (sum_k X[src(r), k] * W[j, k] + b[j]) * scale
// ---------------------------------------------------------------------------
__global__ __launch_bounds__(256) void gemm_proj(
    const float* __restrict__ X, const int* __restrict__ idx,
    const float* __restrict__ W, const float* __restrict__ b,
    float* __restrict__ out, int rows, float scale)
{
  __shared__ __align__(16) float As[16][64];
  __shared__ __align__(16) float Bs[16][64];

  const int tid = threadIdx.x;
  const int tx = tid & 15;
  const int ty = tid >> 4;
  const int i0 = blockIdx.x * 64;
  const int j0 = blockIdx.y * 64;
  const int lk = tid & 15;
  const int lr = tid >> 4;

  float c[4][4];
#pragma unroll
  for (int r = 0; r < 4; r++)
#pragma unroll
    for (int cc = 0; cc < 4; cc++) c[r][cc] = 0.f;

  for (int kt = 0; kt < DIM; kt += 16) {
#pragma unroll
    for (int rr = 0; rr < 4; rr++) {
      const int il = lr + rr * 16;
      const int row = i0 + il;
      float a = 0.f;
      if (row < rows) {
        const int src = idx ? idx[row] : row;
        a = X[src * DIM + kt + lk];
      }
      As[lk][il] = a;
      Bs[lk][il] = W[(j0 + il) * DIM + kt + lk];
    }
    __syncthreads();
#pragma unroll
    for (int kk = 0; kk < 16; kk++) {
      const float4 av = *reinterpret_cast<const float4*>(&As[kk][ty * 4]);
      const float4 bv = *reinterpret_cast<const float4*>(&Bs[kk][tx * 4]);
      const float aa[4] = {av.x, av.y, av.z, av.w};
      const float bb[4] = {bv.x, bv.y, bv.z, bv.w};
#pragma unroll
      for (int r = 0; r < 4; r++)
#pragma unroll
        for (int cc = 0; cc < 4; cc++)
          c[r][cc] = fmaf(aa[r], bb[cc], c[r][cc]);
    }
    __syncthreads();
  }

#pragma unroll
  for (int r = 0; r < 4; r++) {
    const int row = i0 + ty * 4 + r;
    if (row < rows) {
      const int j = j0 + tx * 4;
      float4 o;
      o.x = (c[r][0] + b[j + 0]) * scale;
      o.y = (c[r][1] + b[j + 1]) * scale;
      o.z = (c[r][2] + b[j + 2]) * scale;
      o.w = (c[r][3] + b[j + 3]) * scale;
      *reinterpret_cast<float4*>(&out[row * DIM + j]) = o;
    }
  }
}

// ---------------------------------------------------------------------------
// MFMA flash attention.
// Block = 32 tail rows x all 8 heads. 8 waves, wave = head. s-tiles of 32.
// S^T = K·Q^T  (mfma: A=K frag, B=Q^T frag) -> S^T[s_row, t_col], t = lane&31.
// Softmax over s: 16 in-lane regs + shfl_xor(32) half exchange; per-t stats
// are lane-local. P^T rebuilt as bf16 B-fragments via cvt_pk + cross-half
// shfl/select. O^T = V^T·P^T (A=V^T frag, B=P^T frag) -> O^T[d_row, t_col],
// so rescale/epilogue divide are per-lane broadcasts.
// adj/cind tile staged once per block into LDS (double-buffered), bias via
// per-head 128-entry table: edge_emb[c][h] + (adj ? 0 : -1e9).
// ---------------------------------------------------------------------------
__global__ __launch_bounds__(512, 2) void attn_mfma(
    const float* __restrict__ Qp, const float* __restrict__ Kp,
    const float* __restrict__ Vp, const int* __restrict__ adj,
    const int* __restrict__ cind, const float* __restrict__ edge_emb,
    const int* __restrict__ tail_idx, float* __restrict__ attn_all)
{
  __shared__ float btable[NHEAD][128];
  __shared__ unsigned int ptile[2][32][33];   // [s][t], padded: conflict-free

  const int tid = threadIdx.x;
  const int h = tid >> 6;          // wave = head
  const int lane = tid & 63;
  const int hi = lane >> 5;
  const int lc = lane & 31;        // t-col (S/PV), s-row (K frag), d (V frag)
  const int t0 = blockIdx.x * 32;

  // ---- per-head bias table: idx = c + 64*adjflag
  for (int i = tid; i < NHEAD * 128; i += 512) {
    const int hh = i >> 7, idx = i & 127, c = idx & 63, a = idx >> 6;
    btable[hh][idx] = edge_emb[c * NHEAD + hh] + (a ? 0.f : -1e9f);
  }

  // ---- stage tile 0 (adj/cind packed: c | (adj!=0)<<6), layout [s][t]
  const int sl = tid & 31;
  const int tl = tid >> 5;         // 0..15; second rep = tl+16
  {
    const int r0 = min(t0 + tl, T_N - 1);
    const int r1 = min(t0 + tl + 16, T_N - 1);
    const unsigned int p0 =
        ((unsigned)cind[(size_t)r0 * H_N + sl] & 63u) | ((adj[(size_t)r0 * H_N + sl] != 0) << 6);
    const unsigned int p1 =
        ((unsigned)cind[(size_t)r1 * H_N + sl] & 63u) | ((adj[(size_t)r1 * H_N + sl] != 0) << 6);
    ptile[0][sl][tl] = p0;
    ptile[0][sl][tl + 16] = p1;
  }

  // ---- Q fragments (B operand of QK^T): lane holds Q[t0+lc, kk*16+hi*8+e]
  bf16x8 qf[2];
  {
    const int trow = t0 + lc;
#pragma unroll
    for (int kk = 0; kk < 2; kk++) {
      BF8U u;
      if (trow < T_N) {
        const float* src = Qp + (size_t)trow * DIM + h * HDIM + kk * 16 + hi * 8;
        const float4 x0 = *reinterpret_cast<const float4*>(src);
        const float4 x1 = *reinterpret_cast<const float4*>(src + 4);
        u.h[0] = __float2bfloat16(x0.x); u.h[1] = __float2bfloat16(x0.y);
        u.h[2] = __float2bfloat16(x0.z); u.h[3] = __float2bfloat16(x0.w);
        u.h[4] = __float2bfloat16(x1.x); u.h[5] = __float2bfloat16(x1.y);
        u.h[6] = __float2bfloat16(x1.z); u.h[7] = __float2bfloat16(x1.w);
      } else {
        u.w[0] = 0; u.w[1] = 0; u.w[2] = 0; u.w[3] = 0;
      }
      qf[kk] = u.v;
    }
  }

  f32x16 oacc;
#pragma unroll
  for (int r = 0; r < 16; r++) oacc[r] = 0.f;
  float m = -3e38f, lsum = 0.f;

  __syncthreads();

  const int NT = H_N / 32;  // 125
  for (int it = 0; it < NT; it++) {
    const int cur = it & 1;
    const int s0 = it * 32;

    // -- issue next-tile global loads early (latency hides under compute)
    unsigned int np0 = 0, np1 = 0;
    if (it + 1 < NT) {
      const int sb = s0 + 32;
      const int r0 = min(t0 + tl, T_N - 1);
      const int r1 = min(t0 + tl + 16, T_N - 1);
      np0 = ((unsigned)cind[(size_t)r0 * H_N + sb + sl] & 63u) |
            ((adj[(size_t)r0 * H_N + sb + sl] != 0) << 6);
      np1 = ((unsigned)cind[(size_t)r1 * H_N + sb + sl] & 63u) |
            ((adj[(size_t)r1 * H_N + sb + sl] != 0) << 6);
    }

    // -- K fragments (A operand): lane holds K[s0+lc, kk*16+hi*8+e]
    bf16x8 kf[2];
#pragma unroll
    for (int kk = 0; kk < 2; kk++) {
      const float* src = Kp + (size_t)(s0 + lc) * DIM + h * HDIM + kk * 16 + hi * 8;
      const float4 x0 = *reinterpret_cast<const float4*>(src);
      const float4 x1 = *reinterpret_cast<const float4*>(src + 4);
      BF8U u;
      u.h[0] = __float2bfloat16(x0.x); u.h[1] = __float2bfloat16(x0.y);
      u.h[2] = __float2bfloat16(x0.z); u.h[3] = __float2bfloat16(x0.w);
      u.h[4] = __float2bfloat16(x1.x); u.h[5] = __float2bfloat16(x1.y);
      u.h[6] = __float2bfloat16(x1.z); u.h[7] = __float2bfloat16(x1.w);
      kf[kk] = u.v;
    }

    // -- S^T = K · Q^T
    f32x16 z;
#pragma unroll
    for (int r = 0; r < 16; r++) z[r] = 0.f;
    f32x16 sa = __builtin_amdgcn_mfma_f32_32x32x16_bf16(kf[0], qf[0], z, 0, 0, 0);
    sa = __builtin_amdgcn_mfma_f32_32x32x16_bf16(kf[1], qf[1], sa, 0, 0, 0);

    // -- bias + online softmax (per t = lane&31; s in 16 regs + partner half)
    float p[16];
    float pmax = -3e38f;
#pragma unroll
    for (int r = 0; r < 16; r++) {
      const int srow = (r & 3) + 8 * (r >> 2) + 4 * hi;
      const float bias = btable[h][ptile[cur][srow][lc] & 127u];
      p[r] = sa[r] + bias;
      pmax = fmaxf(pmax, p[r]);
    }
    pmax = fmaxf(pmax, __shfl_xor(pmax, 32));
    const float mnew = fmaxf(m, pmax);
    const float corr = __expf(m - mnew);
    float psum = 0.f;
#pragma unroll
    for (int r = 0; r < 16; r++) {
      p[r] = __expf(p[r] - mnew);
      psum += p[r];
    }
    psum += __shfl_xor(psum, 32);
    lsum = lsum * corr + psum;
    m = mnew;
#pragma unroll
    for (int r = 0; r < 16; r++) oacc[r] *= corr;

    // -- P^T bf16 fragments. p[r] holds s=(r&3)+8*(r>>2)+4*hi for t=lc.
    //    Need elem e of frag kks to be s = kks*16 + hi*8 + e.
    const unsigned int A0 = cvt_pk_bf16(p[0], p[1]);
    const unsigned int A1 = cvt_pk_bf16(p[2], p[3]);
    const unsigned int B0 = cvt_pk_bf16(p[4], p[5]);
    const unsigned int B1 = cvt_pk_bf16(p[6], p[7]);
    const unsigned int C0 = cvt_pk_bf16(p[8], p[9]);
    const unsigned int C1 = cvt_pk_bf16(p[10], p[11]);
    const unsigned int E0 = cvt_pk_bf16(p[12], p[13]);
    const unsigned int E1 = cvt_pk_bf16(p[14], p[15]);
    const unsigned int A0x = __shfl_xor(A0, 32), A1x = __shfl_xor(A1, 32);
    const unsigned int B0x = __shfl_xor(B0, 32), B1x = __shfl_xor(B1, 32);
    const unsigned int C0x = __shfl_xor(C0, 32), C1x = __shfl_xor(C1, 32);
    const unsigned int E0x = __shfl_xor(E0, 32), E1x = __shfl_xor(E1, 32);
    BF8U pu0, pu1;
    pu0.w[0] = hi ? B0x : A0;  pu0.w[1] = hi ? B1x : A1;
    pu0.w[2] = hi ? B0 : A0x;  pu0.w[3] = hi ? B1 : A1x;
    pu1.w[0] = hi ? E0x : C0;  pu1.w[1] = hi ? E1x : C1;
    pu1.w[2] = hi ? E0 : C0x;  pu1.w[3] = hi ? E1 : C1x;

    // -- V^T fragments (A operand): lane holds V[s0+kks*16+hi*8+e, d=lc]
#pragma unroll
    for (int kks = 0; kks < 2; kks++) {
      BF8U vu;
      const float* vbase = Vp + (size_t)(s0 + kks * 16 + hi * 8) * DIM + h * HDIM + lc;
#pragma unroll
      for (int e = 0; e < 8; e++) vu.h[e] = __float2bfloat16(vbase[(size_t)e * DIM]);
      oacc = __builtin_amdgcn_mfma_f32_32x32x16_bf16(
          vu.v, kks ? pu1.v : pu0.v, oacc, 0, 0, 0);
    }

    // -- stage next tile into the other buffer, one barrier per iter
    if (it + 1 < NT) {
      ptile[cur ^ 1][sl][tl] = np0;
      ptile[cur ^ 1][sl][tl + 16] = np1;
    }
    __syncthreads();
  }

  // ---- epilogue: O^T[d_row, t_col] / l(t);  t = lc is lane-local
  const int trow = t0 + lc;
  if (trow < T_N) {
    const int orow = tail_idx[trow];
    const float inv = 1.f / lsum;
#pragma unroll
    for (int r = 0; r < 16; r++) {
      const int d = (r & 3) + 8 * (r >> 2) + 4 * hi;
      attn_all[(size_t)orow * DIM + h * HDIM + d] = oacc[r] * inv;
    }
  }
}

// ---------------------------------------------------------------------------
__global__ __launch_bounds__(64) void copy_head_rows(
    const float* __restrict__ query, const int* __restrict__ head_idx,
    float* __restrict__ attn_all)
{
  const int s = blockIdx.x;
  const int row = head_idx[s];
  const int lane = threadIdx.x;
  const float4* src = reinterpret_cast<const float4*>(&query[row * DIM]);
  float4* dst = reinterpret_cast<float4*>(&attn_all[row * DIM]);
  dst[lane] = src[lane];
}

// ---------------------------------------------------------------------------
extern "C" void kernel_launch(void* const* d_in, const int* in_sizes, int n_in,
                              void* d_out, int out_size, void* d_ws, size_t ws_size,
                              hipStream_t stream)
{
  const float* query    = (const float*)d_in[0];
  const float* key      = (const float*)d_in[1];
  const float* value    = (const float*)d_in[2];
  const int*   adj      = (const int*)d_in[3];
  const int*   cind     = (const int*)d_in[4];
  const int*   tail_idx = (const int*)d_in[5];
  const int*   head_idx = (const int*)d_in[6];
  const float* Wq = (const float*)d_in[7];
  const float* bq = (const float*)d_in[8];
  const float* Wk = (const float*)d_in[9];
  const float* bk = (const float*)d_in[10];
  const float* Wv = (const float*)d_in[11];
  const float* bv = (const float*)d_in[12];
  const float* Wo = (const float*)d_in[13];
  const float* bo = (const float*)d_in[14];
  const float* edge_emb = (const float*)d_in[15];

  float* out = (float*)d_out;
  float* ws  = (float*)d_ws;

  float* Qp   = ws;                          // T_N * DIM
  float* Kp   = Qp + (size_t)T_N * DIM;      // H_N * DIM
  float* Vp   = Kp + (size_t)H_N * DIM;      // H_N * DIM
  float* attn = Vp + (size_t)H_N * DIM;      // N_N * DIM

  hipMemsetAsync(attn, 0, (size_t)N_N * DIM * sizeof(float), stream);

  const dim3 blk(256);
  gemm_proj<<<dim3((T_N + 63) / 64, DIM / 64), blk, 0, stream>>>(
      query, tail_idx, Wq, bq, Qp, T_N, SCALING);
  gemm_proj<<<dim3((H_N + 63) / 64, DIM / 64), blk, 0, stream>>>(
      key, head_idx, Wk, bk, Kp, H_N, 1.f);
  gemm_proj<<<dim3((H_N + 63) / 64, DIM / 64), blk, 0, stream>>>(
      value, head_idx, Wv, bv, Vp, H_N, 1.f);

  attn_mfma<<<dim3((T_N + 31) / 32), dim3(512), 0, stream>>>(
      Qp, Kp, Vp, adj, cind, edge_emb, tail_idx, attn);
  copy_head_rows<<<dim3(H_N), dim3(64), 0, stream>>>(query, head_idx, attn);

  gemm_proj<<<dim3((N_N + 63) / 64, DIM / 64), blk, 0, stream>>>(
      attn, nullptr, Wo, bo, out, N_N, 1.f);
}

// Round 3
// 318.766 us; speedup vs baseline: 25.3688x; 1.2706x over previous
//
#include <hip/hip_runtime.h>
#include <hip/hip_bf16.h>

#define T_N 6000
#define H_N 4000
#define N_N 12000
#define DIM 256
#define NHEAD 8
#define HDIM 32
#define SCALING 0.17677669529663687f  // 32^-0.5

typedef __attribute__((ext_vector_type(8))) short bf16x8;
typedef __attribute__((ext_vector_type(4))) float f32x4;

union BF8U { bf16x8 v; unsigned int w[4]; __hip_bfloat16 h[8]; };

static __device__ __forceinline__ unsigned int cvt_pk_bf16(float a, float b) {
  unsigned int r;
  asm("v_cvt_pk_bf16_f32 %0, %1, %2" : "=v"(r) : "v"(a), "v"(b));
  return r;
}

// ---------------------------------------------------------------------------
// GEMM: out[r, j] = (sum_k X[src(r), k] * W[j, k] + b[j]) * scale
// OM=0: f32 [rows][DIM]; OM=1: bf16 [rows][DIM]; OM=2: bf16 transposed [DIM][ldT]
// ---------------------------------------------------------------------------
template <int OM>
__global__ __launch_bounds__(256) void gemm_proj(
    const float* __restrict__ X, const int* __restrict__ idx,
    const float* __restrict__ W, const float* __restrict__ b,
    void* __restrict__ outv, int rows, int ldT, float scale)
{
  __shared__ __align__(16) float As[16][64];
  __shared__ __align__(16) float Bs[16][64];

  const int tid = threadIdx.x;
  const int tx = tid & 15;
  const int ty = tid >> 4;
  const int i0 = blockIdx.x * 64;
  const int j0 = blockIdx.y * 64;
  const int lk = tid & 15;
  const int lr = tid >> 4;

  float c[4][4];
#pragma unroll
  for (int r = 0; r < 4; r++)
#pragma unroll
    for (int cc = 0; cc < 4; cc++) c[r][cc] = 0.f;

  for (int kt = 0; kt < DIM; kt += 16) {
#pragma unroll
    for (int rr = 0; rr < 4; rr++) {
      const int il = lr + rr * 16;
      const int row = i0 + il;
      float a = 0.f;
      if (row < rows) {
        const int src = idx ? idx[row] : row;
        a = X[src * DIM + kt + lk];
      }
      As[lk][il] = a;
      Bs[lk][il] = W[(j0 + il) * DIM + kt + lk];
    }
    __syncthreads();
#pragma unroll
    for (int kk = 0; kk < 16; kk++) {
      const float4 av = *reinterpret_cast<const float4*>(&As[kk][ty * 4]);
      const float4 bv = *reinterpret_cast<const float4*>(&Bs[kk][tx * 4]);
      const float aa[4] = {av.x, av.y, av.z, av.w};
      const float bb[4] = {bv.x, bv.y, bv.z, bv.w};
#pragma unroll
      for (int r = 0; r < 4; r++)
#pragma unroll
        for (int cc = 0; cc < 4; cc++)
          c[r][cc] = fmaf(aa[r], bb[cc], c[r][cc]);
    }
    __syncthreads();
  }

#pragma unroll
  for (int r = 0; r < 4; r++) {
    const int row = i0 + ty * 4 + r;
    if (row < rows) {
      const int j = j0 + tx * 4;
      float4 o;
      o.x = (c[r][0] + b[j + 0]) * scale;
      o.y = (c[r][1] + b[j + 1]) * scale;
      o.z = (c[r][2] + b[j + 2]) * scale;
      o.w = (c[r][3] + b[j + 3]) * scale;
      if (OM == 0) {
        float* out = (float*)outv;
        *reinterpret_cast<float4*>(&out[(size_t)row * DIM + j]) = o;
      } else if (OM == 1) {
        __hip_bfloat16* out = (__hip_bfloat16*)outv;
        uint2 pr;
        pr.x = cvt_pk_bf16(o.x, o.y);
        pr.y = cvt_pk_bf16(o.z, o.w);
        *reinterpret_cast<uint2*>(&out[(size_t)row * DIM + j]) = pr;
      } else {
        __hip_bfloat16* outT = (__hip_bfloat16*)outv;
        const float ov[4] = {o.x, o.y, o.z, o.w};
#pragma unroll
        for (int cc = 0; cc < 4; cc++)
          outT[(size_t)(j + cc) * ldT + row] = __float2bfloat16(ov[cc]);
      }
    }
  }
}

// ---------------------------------------------------------------------------
// MFMA flash attention, 16x16x32, latency-optimized.
// Grid (375, 2): x = t-tile of 16, y = head-group of 4.
// Block = 256 thr = 8 waves: wave w -> head (y*4 + (w&3)), s-chunk (w>>2).
// Chunk 0: s-tiles [0,63), chunk 1: [63,125). No barriers in main loop;
// chunks merged in-block at the end (one barrier).
// Per s-tile (32 keys):
//   S^T = K·Q^T (2 mfma), bias = bpermute(edge col) + adj mask (regs, no LDS),
//   in-register online softmax (per-t stats lane-local after 2 shfl_xor),
//   P^T rebuilt as bf16 B-frag (4 cvt_pk + 8 shfl + 4 sel),
//   O^T += V^T·P^T (2 mfma). K/V/adj/cind register-prefetched 1 tile ahead.
// ---------------------------------------------------------------------------
__global__ __launch_bounds__(256, 4) void attn_mfma(
    const __hip_bfloat16* __restrict__ Qb, const __hip_bfloat16* __restrict__ Kb,
    const __hip_bfloat16* __restrict__ VbT, const int* __restrict__ adj,
    const int* __restrict__ cind, const float* __restrict__ edge_emb,
    const int* __restrict__ tail_idx, float* __restrict__ attn_all)
{
  __shared__ float mg[4][64][11];   // stride 11: 2-way max on merge (free)

  const int tid = threadIdx.x;
  const int w = tid >> 6;
  const int lane = tid & 63;
  const int g = lane >> 4;
  const int t = lane & 15;
  const int hl = w & 3;
  const int cs = w >> 2;
  const int h = blockIdx.y * 4 + hl;
  const int t0 = blockIdx.x * 16;
  const int hbase = h * HDIM;

  // lane l holds edge_emb[l][h]; bias gather = bpermute (conflict-free)
  const float eval = edge_emb[lane * NHEAD + h];

  // Q B-frag: one 16B bf16 load (lane: col t, k = g*8+e)
  const bf16x8 qu = *reinterpret_cast<const bf16x8*>(
      Qb + (size_t)(t0 + t) * DIM + hbase + g * 8);

  const int itBeg = cs ? 63 : 0;
  const int itEnd = cs ? 125 : 63;

  f32x4 oacc0 = {0.f, 0.f, 0.f, 0.f};
  f32x4 oacc1 = {0.f, 0.f, 0.f, 0.f};
  float m = -3e38f, lsum = 0.f;

  const size_t arow = (size_t)(t0 + t) * H_N;

  // ---- prefetch tile itBeg into regs
  int4 nc0, nc1, na0, na1;
  bf16x8 nk0, nk1, nv0, nv1;
  {
    const int s0 = itBeg * 32;
    const size_t rb = arow + s0 + g * 4;
    nc0 = *reinterpret_cast<const int4*>(cind + rb);
    nc1 = *reinterpret_cast<const int4*>(cind + rb + 16);
    na0 = *reinterpret_cast<const int4*>(adj + rb);
    na1 = *reinterpret_cast<const int4*>(adj + rb + 16);
    const __hip_bfloat16* kp = Kb + (size_t)(s0 + t) * DIM + hbase + g * 8;
    nk0 = *reinterpret_cast<const bf16x8*>(kp);
    nk1 = *reinterpret_cast<const bf16x8*>(kp + (size_t)16 * DIM);
    const __hip_bfloat16* vp = VbT + (size_t)(hbase + t) * H_N + s0 + g * 8;
    nv0 = *reinterpret_cast<const bf16x8*>(vp);
    nv1 = *reinterpret_cast<const bf16x8*>(vp + (size_t)16 * H_N);
  }

  for (int it = itBeg; it < itEnd; ++it) {
    const int4 c0 = nc0, c1 = nc1, a0 = na0, a1 = na1;
    const bf16x8 kf0 = nk0, kf1 = nk1, vf0 = nv0, vf1 = nv1;

    // S^T halves: C reg r -> s = mm*16 + g*4 + r, col t
    const f32x4 z = {0.f, 0.f, 0.f, 0.f};
    const f32x4 s_lo = __builtin_amdgcn_mfma_f32_16x16x32_bf16(kf0, qu, z, 0, 0, 0);
    const f32x4 s_hi = __builtin_amdgcn_mfma_f32_16x16x32_bf16(kf1, qu, z, 0, 0, 0);

    // issue next-tile loads (consumed next iter)
    if (it + 1 < itEnd) {
      const int sn = (it + 1) * 32;
      const size_t rb = arow + sn + g * 4;
      nc0 = *reinterpret_cast<const int4*>(cind + rb);
      nc1 = *reinterpret_cast<const int4*>(cind + rb + 16);
      na0 = *reinterpret_cast<const int4*>(adj + rb);
      na1 = *reinterpret_cast<const int4*>(adj + rb + 16);
      const __hip_bfloat16* kp = Kb + (size_t)(sn + t) * DIM + hbase + g * 8;
      nk0 = *reinterpret_cast<const bf16x8*>(kp);
      nk1 = *reinterpret_cast<const bf16x8*>(kp + (size_t)16 * DIM);
      const __hip_bfloat16* vp = VbT + (size_t)(hbase + t) * H_N + sn + g * 8;
      nv0 = *reinterpret_cast<const bf16x8*>(vp);
      nv1 = *reinterpret_cast<const bf16x8*>(vp + (size_t)16 * H_N);
    }

    // bias + mask -> p[8]
    float p[8];
    {
      const int cc[8] = {c0.x, c0.y, c0.z, c0.w, c1.x, c1.y, c1.z, c1.w};
      const int aa[8] = {a0.x, a0.y, a0.z, a0.w, a1.x, a1.y, a1.z, a1.w};
      const float sv[8] = {s_lo[0], s_lo[1], s_lo[2], s_lo[3],
                           s_hi[0], s_hi[1], s_hi[2], s_hi[3]};
#pragma unroll
      for (int r = 0; r < 8; r++) {
        const float bias = __shfl(eval, cc[r], 64);
        p[r] = sv[r] + bias + (aa[r] ? 0.f : -1e9f);
      }
    }

    // online softmax: per-t reduce over the 4 g-groups (lanes t, t+16, t+32, t+48)
    float pmax = p[0];
#pragma unroll
    for (int r = 1; r < 8; r++) pmax = fmaxf(pmax, p[r]);
    pmax = fmaxf(pmax, __shfl_xor(pmax, 16, 64));
    pmax = fmaxf(pmax, __shfl_xor(pmax, 32, 64));
    const float mnew = fmaxf(m, pmax);
    const float corr = __expf(m - mnew);
    float psum = 0.f;
#pragma unroll
    for (int r = 0; r < 8; r++) {
      p[r] = __expf(p[r] - mnew);
      psum += p[r];
    }
    psum += __shfl_xor(psum, 16, 64);
    psum += __shfl_xor(psum, 32, 64);
    lsum = lsum * corr + psum;
    m = mnew;
#pragma unroll
    for (int r = 0; r < 4; r++) { oacc0[r] *= corr; oacc1[r] *= corr; }

    // P^T -> bf16 B-frag (elem e: s = g*8+e, col t)
    const unsigned int w00 = cvt_pk_bf16(p[0], p[1]);
    const unsigned int w01 = cvt_pk_bf16(p[2], p[3]);
    const unsigned int w10 = cvt_pk_bf16(p[4], p[5]);
    const unsigned int w11 = cvt_pk_bf16(p[6], p[7]);
    const int lA = ((g & 1) * 2) * 16 + t;
    const int lB = lA + 16;
    const unsigned int x0a = __shfl(w00, lA, 64), x0b = __shfl(w10, lA, 64);
    const unsigned int x1a = __shfl(w01, lA, 64), x1b = __shfl(w11, lA, 64);
    const unsigned int x2a = __shfl(w00, lB, 64), x2b = __shfl(w10, lB, 64);
    const unsigned int x3a = __shfl(w01, lB, 64), x3b = __shfl(w11, lB, 64);
    const bool hiH = (g >> 1) != 0;
    BF8U pu;
    pu.w[0] = hiH ? x0b : x0a;
    pu.w[1] = hiH ? x1b : x1a;
    pu.w[2] = hiH ? x2b : x2a;
    pu.w[3] = hiH ? x3b : x3a;

    // O^T += V^T · P^T (d halves)
    oacc0 = __builtin_amdgcn_mfma_f32_16x16x32_bf16(vf0, pu.v, oacc0, 0, 0, 0);
    oacc1 = __builtin_amdgcn_mfma_f32_16x16x32_bf16(vf1, pu.v, oacc1, 0, 0, 0);
  }

  // ---- merge chunk 1 into chunk 0, then epilogue
  if (cs) {
#pragma unroll
    for (int r = 0; r < 4; r++) {
      mg[hl][lane][r] = oacc0[r];
      mg[hl][lane][4 + r] = oacc1[r];
    }
    mg[hl][lane][8] = m;
    mg[hl][lane][9] = lsum;
  }
  __syncthreads();
  if (!cs) {
    const float m2 = mg[hl][lane][8];
    const float l2 = mg[hl][lane][9];
    const float Mn = fmaxf(m, m2);
    const float e1 = __expf(m - Mn);
    const float e2 = __expf(m2 - Mn);
    const float L = lsum * e1 + l2 * e2;
    const float inv = 1.f / L;
    const int row = tail_idx[t0 + t];
    float4 o0, o1;
    o0.x = (oacc0[0] * e1 + mg[hl][lane][0] * e2) * inv;
    o0.y = (oacc0[1] * e1 + mg[hl][lane][1] * e2) * inv;
    o0.z = (oacc0[2] * e1 + mg[hl][lane][2] * e2) * inv;
    o0.w = (oacc0[3] * e1 + mg[hl][lane][3] * e2) * inv;
    o1.x = (oacc1[0] * e1 + mg[hl][lane][4] * e2) * inv;
    o1.y = (oacc1[1] * e1 + mg[hl][lane][5] * e2) * inv;
    o1.z = (oacc1[2] * e1 + mg[hl][lane][6] * e2) * inv;
    o1.w = (oacc1[3] * e1 + mg[hl][lane][7] * e2) * inv;
    // oacc reg r -> d = dh*16 + g*4 + r: two float4 stores per lane
    float* dst = attn_all + (size_t)row * DIM + hbase + g * 4;
    *reinterpret_cast<float4*>(dst) = o0;
    *reinterpret_cast<float4*>(dst + 16) = o1;
  }
}

// ---------------------------------------------------------------------------
__global__ __launch_bounds__(64) void copy_head_rows(
    const float* __restrict__ query, const int* __restrict__ head_idx,
    float* __restrict__ attn_all)
{
  const int s = blockIdx.x;
  const int row = head_idx[s];
  const int lane = threadIdx.x;
  const float4* src = reinterpret_cast<const float4*>(&query[row * DIM]);
  float4* dst = reinterpret_cast<float4*>(&attn_all[row * DIM]);
  dst[lane] = src[lane];
}

// ---------------------------------------------------------------------------
extern "C" void kernel_launch(void* const* d_in, const int* in_sizes, int n_in,
                              void* d_out, int out_size, void* d_ws, size_t ws_size,
                              hipStream_t stream)
{
  const float* query    = (const float*)d_in[0];
  const float* key      = (const float*)d_in[1];
  const float* value    = (const float*)d_in[2];
  const int*   adj      = (const int*)d_in[3];
  const int*   cind     = (const int*)d_in[4];
  const int*   tail_idx = (const int*)d_in[5];
  const int*   head_idx = (const int*)d_in[6];
  const float* Wq = (const float*)d_in[7];
  const float* bq = (const float*)d_in[8];
  const float* Wk = (const float*)d_in[9];
  const float* bk = (const float*)d_in[10];
  const float* Wv = (const float*)d_in[11];
  const float* bv = (const float*)d_in[12];
  const float* Wo = (const float*)d_in[13];
  const float* bo = (const float*)d_in[14];
  const float* edge_emb = (const float*)d_in[15];

  float* out = (float*)d_out;
  char*  ws  = (char*)d_ws;

  float* attn = (float*)ws;                                   // N_N*DIM f32
  __hip_bfloat16* Qb  = (__hip_bfloat16*)(ws + (size_t)N_N * DIM * 4);
  __hip_bfloat16* Kb  = Qb + (size_t)T_N * DIM;
  __hip_bfloat16* VbT = Kb + (size_t)H_N * DIM;               // [DIM][H_N]

  // Untouched rows of attn_all must be zero (ws is poisoned 0xAA).
  hipMemsetAsync(attn, 0, (size_t)N_N * DIM * sizeof(float), stream);

  const dim3 blk(256);
  gemm_proj<1><<<dim3((T_N + 63) / 64, DIM / 64), blk, 0, stream>>>(
      query, tail_idx, Wq, bq, Qb, T_N, 0, SCALING);
  gemm_proj<1><<<dim3((H_N + 63) / 64, DIM / 64), blk, 0, stream>>>(
      key, head_idx, Wk, bk, Kb, H_N, 0, 1.f);
  gemm_proj<2><<<dim3((H_N + 63) / 64, DIM / 64), blk, 0, stream>>>(
      value, head_idx, Wv, bv, VbT, H_N, H_N, 1.f);

  attn_mfma<<<dim3(T_N / 16, 2), blk, 0, stream>>>(
      Qb, Kb, VbT, adj, cind, edge_emb, tail_idx, attn);
  copy_head_rows<<<dim3(H_N), dim3(64), 0, stream>>>(query, head_idx, attn);

  gemm_proj<0><<<dim3((N_N + 63) / 64, DIM / 64), blk, 0, stream>>>(
      attn, nullptr, Wo, bo, out, N_N, 0, 1.f);
}

// Round 4
// 272.598 us; speedup vs baseline: 29.6653x; 1.1694x over previous
//
#include <hip/hip_runtime.h>
#include <hip/hip_bf16.h>

#define T_N 6000
#define H_N 4000
#define N_N 12000
#define DIM 256
#define NHEAD 8
#define HDIM 32
#define SCALING 0.17677669529663687f  // 32^-0.5
#define NTT 375   // T_N/16 t-tiles
#define NST 125   // H_N/32 s-tiles

typedef __attribute__((ext_vector_type(8))) short bf16x8;
typedef __attribute__((ext_vector_type(4))) float f32x4;

union BF8U { bf16x8 v; unsigned int w[4]; __hip_bfloat16 h[8]; };

static __device__ __forceinline__ unsigned int cvt_pk_bf16(float a, float b) {
  unsigned int r;
  asm("v_cvt_pk_bf16_f32 %0, %1, %2" : "=v"(r) : "v"(a), "v"(b));
  return r;
}

// ---------------------------------------------------------------------------
// pack adj+cind into 7-bit codes (c | adj<<6), laid out in S^T C-frag order:
// uint32 index = ((tt*NST + st)*8 + gi)*16 + tl ; byte k of the word holds
// s_local = gi*4 + k for tail row t = tt*16+tl. 4 B/thread, writes coalesced.
// ---------------------------------------------------------------------------
__global__ __launch_bounds__(256) void pack_pc(
    const int* __restrict__ adj, const int* __restrict__ cind,
    unsigned int* __restrict__ pc)
{
  const int i = blockIdx.x * 256 + threadIdx.x;
  if (i >= NTT * NST * 128) return;
  const int tl = i & 15;
  const int gi = (i >> 4) & 7;
  const int rem = i >> 7;            // tt*NST + st
  const int st = rem % NST;
  const int tt = rem / NST;
  const int t = tt * 16 + tl;
  const int s0 = st * 32 + gi * 4;
  const int4 c4 = *reinterpret_cast<const int4*>(cind + (size_t)t * H_N + s0);
  const int4 a4 = *reinterpret_cast<const int4*>(adj + (size_t)t * H_N + s0);
  unsigned int w = 0;
  w |= (unsigned)((c4.x & 63) | (a4.x ? 64 : 0));
  w |= (unsigned)((c4.y & 63) | (a4.y ? 64 : 0)) << 8;
  w |= (unsigned)((c4.z & 63) | (a4.z ? 64 : 0)) << 16;
  w |= (unsigned)((c4.w & 63) | (a4.w ? 64 : 0)) << 24;
  pc[i] = w;
}

// ---------------------------------------------------------------------------
// GEMM: v = (sum_k X[src(r),k] * W[j,k] + b[j]) * scale, scattered to
// MFMA fragment layouts.  OM=1: Qf  OM=2: Kf  OM=3: Vf  (bf16).
//   Qf: ((h*NTT + t>>4)*64 + q*16 + (t&15))*8 + e         (q=(j&31)>>3, e=j&7)
//   Kf: ((h*250 + s>>4)*64 + q*16 + (s&15))*8 + e
//   Vf: (((h*2+dh)*NST + s>>5)*64 + ((s&31)>>3)*16 + dl)*8 + (s&7)
//        (dh=(j&31)>>4, dl=j&15)
// ---------------------------------------------------------------------------
template <int OM>
__global__ __launch_bounds__(256) void gemm_proj(
    const float* __restrict__ X, const int* __restrict__ idx,
    const float* __restrict__ W, const float* __restrict__ b,
    __hip_bfloat16* __restrict__ outf, int rows, float scale)
{
  __shared__ __align__(16) float As[16][64];
  __shared__ __align__(16) float Bs[16][64];

  const int tid = threadIdx.x;
  const int tx = tid & 15;
  const int ty = tid >> 4;
  const int i0 = blockIdx.x * 64;
  const int j0 = blockIdx.y * 64;
  const int lk = tid & 15;
  const int lr = tid >> 4;

  float c[4][4];
#pragma unroll
  for (int r = 0; r < 4; r++)
#pragma unroll
    for (int cc = 0; cc < 4; cc++) c[r][cc] = 0.f;

  for (int kt = 0; kt < DIM; kt += 16) {
#pragma unroll
    for (int rr = 0; rr < 4; rr++) {
      const int il = lr + rr * 16;
      const int row = i0 + il;
      float a = 0.f;
      if (row < rows) {
        const int src = idx ? idx[row] : row;
        a = X[(size_t)src * DIM + kt + lk];
      }
      As[lk][il] = a;
      Bs[lk][il] = W[(size_t)(j0 + il) * DIM + kt + lk];
    }
    __syncthreads();
#pragma unroll
    for (int kk = 0; kk < 16; kk++) {
      const float4 av = *reinterpret_cast<const float4*>(&As[kk][ty * 4]);
      const float4 bv = *reinterpret_cast<const float4*>(&Bs[kk][tx * 4]);
      const float aa[4] = {av.x, av.y, av.z, av.w};
      const float bb[4] = {bv.x, bv.y, bv.z, bv.w};
#pragma unroll
      for (int r = 0; r < 4; r++)
#pragma unroll
        for (int cc = 0; cc < 4; cc++)
          c[r][cc] = fmaf(aa[r], bb[cc], c[r][cc]);
    }
    __syncthreads();
  }

#pragma unroll
  for (int r = 0; r < 4; r++) {
    const int row = i0 + ty * 4 + r;
    if (row >= rows) continue;
#pragma unroll
    for (int cc = 0; cc < 4; cc++) {
      const int j = j0 + tx * 4 + cc;
      const float v = (c[r][cc] + b[j]) * scale;
      const __hip_bfloat16 hv = __float2bfloat16(v);
      const int h = j >> 5;
      size_t idxo;
      if (OM == 1) {
        idxo = (((size_t)h * NTT + (row >> 4)) * 64 + ((j & 31) >> 3) * 16 +
                (row & 15)) * 8 + (j & 7);
      } else if (OM == 2) {
        idxo = (((size_t)h * 250 + (row >> 4)) * 64 + ((j & 31) >> 3) * 16 +
                (row & 15)) * 8 + (j & 7);
      } else {
        const int dh = (j & 31) >> 4, dl = j & 15;
        idxo = ((((size_t)h * 2 + dh) * NST + (row >> 5)) * 64 +
                ((row & 31) >> 3) * 16 + dl) * 8 + (row & 7);
      }
      outf[idxo] = hv;
    }
  }
}

// ---------------------------------------------------------------------------
// MFMA flash attention (16x16x32). Block = 256 thr = 4 waves = 2 heads x 2
// s-chunks; grid (375, 4). All main-loop loads are contiguous fragment reads.
// ---------------------------------------------------------------------------
template <bool PACKED>
__global__ __launch_bounds__(256, 5) void attn_mfma(
    const __hip_bfloat16* __restrict__ Qf, const __hip_bfloat16* __restrict__ Kf,
    const __hip_bfloat16* __restrict__ Vf, const unsigned int* __restrict__ pc,
    const int* __restrict__ adj, const int* __restrict__ cind,
    const float* __restrict__ edge_emb, const int* __restrict__ tail_idx,
    __hip_bfloat16* __restrict__ Ab)
{
  __shared__ float mg[2][64][12];

  const int tid = threadIdx.x;
  const int w = tid >> 6;
  const int lane = tid & 63;
  const int q = lane >> 4;
  const int t = lane & 15;
  const int hl = w & 1;
  const int cs = w >> 1;
  const int h = blockIdx.y * 2 + hl;
  const int tt = blockIdx.x;
  const int hbase = h * HDIM;

  // lane l holds edge_emb[l][h]; bias gather = 1 bpermute
  const float eval = edge_emb[lane * NHEAD + h];

  const bf16x8 qf = *reinterpret_cast<const bf16x8*>(
      Qf + (((size_t)h * NTT + tt) * 64 + lane) * 8);

  const int stBeg = cs ? 63 : 0;
  const int stEnd = cs ? NST : 63;

  const unsigned int* pcp = pc + (size_t)(tt * NST + stBeg) * 128 + q * 16 + t;
  const __hip_bfloat16* kp = Kf + (((size_t)h * 250 + stBeg * 2) * 64 + lane) * 8;
  const __hip_bfloat16* vp = Vf + (((size_t)h * 2 * NST + stBeg) * 64 + lane) * 8;
  const size_t VD = (size_t)NST * 64 * 8;
  const int* crow = cind + (size_t)(tt * 16 + t) * H_N;
  const int* arow = adj + (size_t)(tt * 16 + t) * H_N;

  f32x4 oacc0 = {0.f, 0.f, 0.f, 0.f};
  f32x4 oacc1 = {0.f, 0.f, 0.f, 0.f};
  float m = -3e38f, lsum = 0.f;

  unsigned int npc0 = 0, npc1 = 0;
  int4 ncl, nch, nal, nah;
  bf16x8 nk0, nk1, nv0, nv1;
  if (PACKED) {
    npc0 = pcp[0];
    npc1 = pcp[64];
  } else {
    const int sb = stBeg * 32 + q * 4;
    ncl = *reinterpret_cast<const int4*>(crow + sb);
    nch = *reinterpret_cast<const int4*>(crow + sb + 16);
    nal = *reinterpret_cast<const int4*>(arow + sb);
    nah = *reinterpret_cast<const int4*>(arow + sb + 16);
  }
  nk0 = *reinterpret_cast<const bf16x8*>(kp);
  nk1 = *reinterpret_cast<const bf16x8*>(kp + 512);
  nv0 = *reinterpret_cast<const bf16x8*>(vp);
  nv1 = *reinterpret_cast<const bf16x8*>(vp + VD);

  for (int st = stBeg; st < stEnd; ++st) {
    const unsigned int cpc0 = npc0, cpc1 = npc1;
    const int4 ccl = ncl, cch = nch, cal = nal, cah = nah;
    const bf16x8 kf0 = nk0, kf1 = nk1, vf0 = nv0, vf1 = nv1;

    // S^T = K·Q^T : D reg r -> s_local = (half)*16 + q*4 + r, col t
    const f32x4 z = {0.f, 0.f, 0.f, 0.f};
    const f32x4 s_lo = __builtin_amdgcn_mfma_f32_16x16x32_bf16(kf0, qf, z, 0, 0, 0);
    const f32x4 s_hi = __builtin_amdgcn_mfma_f32_16x16x32_bf16(kf1, qf, z, 0, 0, 0);

    if (st + 1 < stEnd) {
      pcp += 128; kp += 1024; vp += 512;
      if (PACKED) {
        npc0 = pcp[0];
        npc1 = pcp[64];
      } else {
        const int sb = (st + 1) * 32 + q * 4;
        ncl = *reinterpret_cast<const int4*>(crow + sb);
        nch = *reinterpret_cast<const int4*>(crow + sb + 16);
        nal = *reinterpret_cast<const int4*>(arow + sb);
        nah = *reinterpret_cast<const int4*>(arow + sb + 16);
      }
      nk0 = *reinterpret_cast<const bf16x8*>(kp);
      nk1 = *reinterpret_cast<const bf16x8*>(kp + 512);
      nv0 = *reinterpret_cast<const bf16x8*>(vp);
      nv1 = *reinterpret_cast<const bf16x8*>(vp + VD);
    }

    // bias + mask -> p[8];  p[r] <-> s_local = (r&4?16:0) + q*4 + (r&3)
    float p[8];
    if (PACKED) {
#pragma unroll
      for (int r = 0; r < 4; r++) {
        const unsigned b0 = (cpc0 >> (r * 8)) & 0xffu;
        const unsigned b1 = (cpc1 >> (r * 8)) & 0xffu;
        const float e0 = __shfl(eval, (int)(b0 & 63u), 64);
        const float e1 = __shfl(eval, (int)(b1 & 63u), 64);
        p[r] = s_lo[r] + ((b0 & 64u) ? e0 : -1e9f);
        p[r + 4] = s_hi[r] + ((b1 & 64u) ? e1 : -1e9f);
      }
    } else {
      const int cc[8] = {ccl.x, ccl.y, ccl.z, ccl.w, cch.x, cch.y, cch.z, cch.w};
      const int aa[8] = {cal.x, cal.y, cal.z, cal.w, cah.x, cah.y, cah.z, cah.w};
      const float sv[8] = {s_lo[0], s_lo[1], s_lo[2], s_lo[3],
                           s_hi[0], s_hi[1], s_hi[2], s_hi[3]};
#pragma unroll
      for (int r = 0; r < 8; r++) {
        const float e = __shfl(eval, cc[r] & 63, 64);
        p[r] = sv[r] + (aa[r] ? e : -1e9f);
      }
    }

    // online softmax (per-t stats live in lanes t, t+16, t+32, t+48)
    float pmax = p[0];
#pragma unroll
    for (int r = 1; r < 8; r++) pmax = fmaxf(pmax, p[r]);
    pmax = fmaxf(pmax, __shfl_xor(pmax, 16, 64));
    pmax = fmaxf(pmax, __shfl_xor(pmax, 32, 64));
    const float mnew = fmaxf(m, pmax);
    const float corr = __expf(m - mnew);
    float psum = 0.f;
#pragma unroll
    for (int r = 0; r < 8; r++) {
      p[r] = __expf(p[r] - mnew);
      psum += p[r];
    }
    psum += __shfl_xor(psum, 16, 64);
    psum += __shfl_xor(psum, 32, 64);
    lsum = lsum * corr + psum;
    m = mnew;
#pragma unroll
    for (int r = 0; r < 4; r++) { oacc0[r] *= corr; oacc1[r] *= corr; }

    // P^T -> bf16 B-frag (elem e: s_local = q*8+e, col t)
    const unsigned int w00 = cvt_pk_bf16(p[0], p[1]);
    const unsigned int w01 = cvt_pk_bf16(p[2], p[3]);
    const unsigned int w10 = cvt_pk_bf16(p[4], p[5]);
    const unsigned int w11 = cvt_pk_bf16(p[6], p[7]);
    const int lA = ((q & 1) * 2) * 16 + t;
    const int lB = lA + 16;
    const unsigned int x0a = __shfl(w00, lA, 64), x0b = __shfl(w10, lA, 64);
    const unsigned int x1a = __shfl(w01, lA, 64), x1b = __shfl(w11, lA, 64);
    const unsigned int x2a = __shfl(w00, lB, 64), x2b = __shfl(w10, lB, 64);
    const unsigned int x3a = __shfl(w01, lB, 64), x3b = __shfl(w11, lB, 64);
    const bool hiH = (q >> 1) != 0;
    BF8U pu;
    pu.w[0] = hiH ? x0b : x0a;
    pu.w[1] = hiH ? x1b : x1a;
    pu.w[2] = hiH ? x2b : x2a;
    pu.w[3] = hiH ? x3b : x3a;

    // O^T += V^T · P^T
    oacc0 = __builtin_amdgcn_mfma_f32_16x16x32_bf16(vf0, pu.v, oacc0, 0, 0, 0);
    oacc1 = __builtin_amdgcn_mfma_f32_16x16x32_bf16(vf1, pu.v, oacc1, 0, 0, 0);
  }

  // ---- merge the two s-chunks, epilogue (bf16 row-major Ab)
  if (cs) {
#pragma unroll
    for (int r = 0; r < 4; r++) {
      mg[hl][lane][r] = oacc0[r];
      mg[hl][lane][4 + r] = oacc1[r];
    }
    mg[hl][lane][8] = m;
    mg[hl][lane][9] = lsum;
  }
  __syncthreads();
  if (!cs) {
    const float m2 = mg[hl][lane][8];
    const float l2 = mg[hl][lane][9];
    const float Mn = fmaxf(m, m2);
    const float e1 = __expf(m - Mn);
    const float e2 = __expf(m2 - Mn);
    const float L = lsum * e1 + l2 * e2;
    const float inv = 1.f / L;
    float o[8];
#pragma unroll
    for (int r = 0; r < 4; r++) {
      o[r] = (oacc0[r] * e1 + mg[hl][lane][r] * e2) * inv;
      o[4 + r] = (oacc1[r] * e1 + mg[hl][lane][4 + r] * e2) * inv;
    }
    const int row = tail_idx[tt * 16 + t];
    __hip_bfloat16* dst = Ab + (size_t)row * DIM + hbase + q * 4;
    uint2 w0, w1;
    w0.x = cvt_pk_bf16(o[0], o[1]); w0.y = cvt_pk_bf16(o[2], o[3]);
    w1.x = cvt_pk_bf16(o[4], o[5]); w1.y = cvt_pk_bf16(o[6], o[7]);
    *reinterpret_cast<uint2*>(dst) = w0;
    *reinterpret_cast<uint2*>(dst + 16) = w1;
  }
}

// ---------------------------------------------------------------------------
__global__ __launch_bounds__(64) void copy_head_rows(
    const float* __restrict__ query, const int* __restrict__ head_idx,
    __hip_bfloat16* __restrict__ Ab)
{
  const int row = head_idx[blockIdx.x];
  const int lane = threadIdx.x;
  const float4 v = *reinterpret_cast<const float4*>(
      query + (size_t)row * DIM + lane * 4);
  uint2 o;
  o.x = cvt_pk_bf16(v.x, v.y);
  o.y = cvt_pk_bf16(v.z, v.w);
  *reinterpret_cast<uint2*>(Ab + (size_t)row * DIM + lane * 4) = o;
}

// ---------------------------------------------------------------------------
// O-projection: out[r,j] = sum_k Ab[r,k]*Wo[j,k] + bo[j].  MFMA 16x16x32,
// tile 64 rows x 32 cols, K=256 fully LDS-staged (XOR-swizzled), 4 waves.
// ---------------------------------------------------------------------------
__global__ __launch_bounds__(256) void oproj_mfma(
    const __hip_bfloat16* __restrict__ Ab, const float* __restrict__ Wo,
    const float* __restrict__ bo, float* __restrict__ out)
{
  __shared__ __align__(16) char As[64 * 512];   // 32 KB
  __shared__ __align__(16) char Bs[32 * 512];   // 16 KB

  const int tid = threadIdx.x;
  const int w = tid >> 6;
  const int lane = tid & 63;
  const int bl = lane & 15;
  const int q = lane >> 4;
  const int m0 = blockIdx.x * 64;
  const int n0 = blockIdx.y * 32;

  // stage A (bf16, guard rows >= N_N with zeros)
  for (int i = tid; i < 2048; i += 256) {
    const int row = i >> 5, c16 = i & 31;
    bf16x8 v = {0, 0, 0, 0, 0, 0, 0, 0};
    const int gr = m0 + row;
    if (gr < N_N)
      v = *reinterpret_cast<const bf16x8*>(Ab + (size_t)gr * DIM + c16 * 8);
    *reinterpret_cast<bf16x8*>(As + ((row * 512 + c16 * 16) ^ ((row & 7) << 4))) = v;
  }
  // stage B (convert Wo f32 -> bf16)
  for (int i = tid; i < 1024; i += 256) {
    const int row = i >> 5, c16 = i & 31;
    const float* src = Wo + (size_t)(n0 + row) * DIM + c16 * 8;
    const float4 x0 = *reinterpret_cast<const float4*>(src);
    const float4 x1 = *reinterpret_cast<const float4*>(src + 4);
    BF8U u;
    u.w[0] = cvt_pk_bf16(x0.x, x0.y);
    u.w[1] = cvt_pk_bf16(x0.z, x0.w);
    u.w[2] = cvt_pk_bf16(x1.x, x1.y);
    u.w[3] = cvt_pk_bf16(x1.z, x1.w);
    *reinterpret_cast<bf16x8*>(Bs + ((row * 512 + c16 * 16) ^ ((row & 7) << 4))) = u.v;
  }
  __syncthreads();

  f32x4 acc0 = {0.f, 0.f, 0.f, 0.f};
  f32x4 acc1 = {0.f, 0.f, 0.f, 0.f};
#pragma unroll
  for (int kk = 0; kk < 8; kk++) {
    const int arow = w * 16 + bl;
    const bf16x8 af = *reinterpret_cast<const bf16x8*>(
        As + ((arow * 512 + (kk * 32 + q * 8) * 2) ^ ((arow & 7) << 4)));
    const bf16x8 bf0 = *reinterpret_cast<const bf16x8*>(
        Bs + ((bl * 512 + (kk * 32 + q * 8) * 2) ^ ((bl & 7) << 4)));
    const int brow = 16 + bl;
    const bf16x8 bf1 = *reinterpret_cast<const bf16x8*>(
        Bs + ((brow * 512 + (kk * 32 + q * 8) * 2) ^ ((brow & 7) << 4)));
    acc0 = __builtin_amdgcn_mfma_f32_16x16x32_bf16(af, bf0, acc0, 0, 0, 0);
    acc1 = __builtin_amdgcn_mfma_f32_16x16x32_bf16(af, bf1, acc1, 0, 0, 0);
  }

#pragma unroll
  for (int r = 0; r < 4; r++) {
    const int grow = m0 + w * 16 + q * 4 + r;
    if (grow < N_N) {
      const int j0 = n0 + bl;
      const int j1 = n0 + 16 + bl;
      out[(size_t)grow * DIM + j0] = acc0[r] + bo[j0];
      out[(size_t)grow * DIM + j1] = acc1[r] + bo[j1];
    }
  }
}

// ---------------------------------------------------------------------------
extern "C" void kernel_launch(void* const* d_in, const int* in_sizes, int n_in,
                              void* d_out, int out_size, void* d_ws, size_t ws_size,
                              hipStream_t stream)
{
  const float* query    = (const float*)d_in[0];
  const float* key      = (const float*)d_in[1];
  const float* value    = (const float*)d_in[2];
  const int*   adj      = (const int*)d_in[3];
  const int*   cind     = (const int*)d_in[4];
  const int*   tail_idx = (const int*)d_in[5];
  const int*   head_idx = (const int*)d_in[6];
  const float* Wq = (const float*)d_in[7];
  const float* bq = (const float*)d_in[8];
  const float* Wk = (const float*)d_in[9];
  const float* bk = (const float*)d_in[10];
  const float* Wv = (const float*)d_in[11];
  const float* bv = (const float*)d_in[12];
  const float* Wo = (const float*)d_in[13];
  const float* bo = (const float*)d_in[14];
  const float* edge_emb = (const float*)d_in[15];

  float* out = (float*)d_out;
  char*  ws  = (char*)d_ws;

  // workspace layout (bytes)
  __hip_bfloat16* Ab = (__hip_bfloat16*)ws;                       // 6,144,000
  __hip_bfloat16* Qf = (__hip_bfloat16*)(ws + 6144000);           // 3,072,000
  __hip_bfloat16* Kf = (__hip_bfloat16*)(ws + 9216000);           // 2,048,000
  __hip_bfloat16* Vf = (__hip_bfloat16*)(ws + 11264000);          // 2,048,000
  unsigned int*   pc = (unsigned int*)(ws + 13312000);            // 24,000,000
  const bool packed = ws_size >= (size_t)37312000;

  // rows not covered by tail/head scatter must be zero
  hipMemsetAsync(Ab, 0, (size_t)N_N * DIM * sizeof(__hip_bfloat16), stream);

  if (packed)
    pack_pc<<<dim3((NTT * NST * 128 + 255) / 256), dim3(256), 0, stream>>>(
        adj, cind, pc);

  const dim3 blk(256);
  gemm_proj<1><<<dim3((T_N + 63) / 64, DIM / 64), blk, 0, stream>>>(
      query, tail_idx, Wq, bq, Qf, T_N, SCALING);
  gemm_proj<2><<<dim3((H_N + 63) / 64, DIM / 64), blk, 0, stream>>>(
      key, head_idx, Wk, bk, Kf, H_N, 1.f);
  gemm_proj<3><<<dim3((H_N + 63) / 64, DIM / 64), blk, 0, stream>>>(
      value, head_idx, Wv, bv, Vf, H_N, 1.f);

  if (packed)
    attn_mfma<true><<<dim3(NTT, 4), blk, 0, stream>>>(
        Qf, Kf, Vf, pc, adj, cind, edge_emb, tail_idx, Ab);
  else
    attn_mfma<false><<<dim3(NTT, 4), blk, 0, stream>>>(
        Qf, Kf, Vf, pc, adj, cind, edge_emb, tail_idx, Ab);

  copy_head_rows<<<dim3(H_N), dim3(64), 0, stream>>>(query, head_idx, Ab);

  oproj_mfma<<<dim3((N_N + 63) / 64, DIM / 32), blk, 0, stream>>>(
      Ab, Wo, bo, out);
}

// Round 5
// 172.162 us; speedup vs baseline: 46.9714x; 1.5834x over previous
//
#include <hip/hip_runtime.h>
#include <hip/hip_bf16.h>

#define T_N 6000
#define H_N 4000
#define N_N 12000
#define DIM 256
#define NHEAD 8
#define HDIM 32
#define SCALING 0.17677669529663687f  // 32^-0.5
#define NTT 375   // T_N/16 t-tiles
#define NST 125   // H_N/32 s-tiles

typedef __attribute__((ext_vector_type(8))) short bf16x8;
typedef __attribute__((ext_vector_type(4))) float f32x4;

union BF8U { bf16x8 v; unsigned int w[4]; __hip_bfloat16 h[8]; };

static __device__ __forceinline__ unsigned int cvt_pk_bf16(float a, float b) {
  unsigned int r;
  asm("v_cvt_pk_bf16_f32 %0, %1, %2" : "=v"(r) : "v"(a), "v"(b));
  return r;
}

// ---------------------------------------------------------------------------
// pack adj+cind into 7-bit codes (c | adj<<6), in S^T C-frag order:
// word index = ((tt*NST + st)*8 + gi)*16 + tl ; byte k holds s_local = gi*4+k.
// ---------------------------------------------------------------------------
__global__ __launch_bounds__(256) void pack_pc(
    const int* __restrict__ adj, const int* __restrict__ cind,
    unsigned int* __restrict__ pc)
{
  const int i = blockIdx.x * 256 + threadIdx.x;
  if (i >= NTT * NST * 128) return;
  const int tl = i & 15;
  const int gi = (i >> 4) & 7;
  const int rem = i >> 7;            // tt*NST + st
  const int st = rem % NST;
  const int tt = rem / NST;
  const int t = tt * 16 + tl;
  const int s0 = st * 32 + gi * 4;
  const int4 c4 = *reinterpret_cast<const int4*>(cind + (size_t)t * H_N + s0);
  const int4 a4 = *reinterpret_cast<const int4*>(adj + (size_t)t * H_N + s0);
  unsigned int w = 0;
  w |= (unsigned)((c4.x & 63) | (a4.x ? 64 : 0));
  w |= (unsigned)((c4.y & 63) | (a4.y ? 64 : 0)) << 8;
  w |= (unsigned)((c4.z & 63) | (a4.z ? 64 : 0)) << 16;
  w |= (unsigned)((c4.w & 63) | (a4.w ? 64 : 0)) << 24;
  pc[i] = w;
}

// ---------------------------------------------------------------------------
// bf16 MFMA projection: out = (X[src]·W^T + b)·scale, scattered to fragment
// layouts. Tile 64 rows x 32 cols, K=256 fully LDS-staged (XOR-swizzled).
// Grid (8, nRowTiles): consecutive blocks share the X row-tile (L2 reuse).
//   OM=1: Qf   ((h*NTT + r>>4)*64 + q*16 + (r&15))*8 + e     q=(j&31)>>3,e=j&7
//   OM=2: Kf   ((h*250 + r>>4)*64 + q*16 + (r&15))*8 + e
//   OM=3: Vf   permuted-s: sl=r&31, qv=(sl&15)>>2, ev=(sl&3)|((sl>>4)<<2)
//              (((h*2+dh)*NST + r>>5)*64 + qv*16 + dl)*8 + ev  dh=(j&31)>>4,dl=j&15
// ---------------------------------------------------------------------------
template <int OM>
__global__ __launch_bounds__(256) void proj_mfma(
    const float* __restrict__ X, const int* __restrict__ idx,
    const float* __restrict__ W, const float* __restrict__ b,
    __hip_bfloat16* __restrict__ outf, int rows, float scale)
{
  __shared__ __align__(16) char As[64 * 512];   // 32 KB
  __shared__ __align__(16) char Bs[32 * 512];   // 16 KB

  const int tid = threadIdx.x;
  const int w = tid >> 6;
  const int lane = tid & 63;
  const int q = lane >> 4;
  const int t = lane & 15;
  const int n0 = blockIdx.x * 32;
  const int m0 = blockIdx.y * 64;

  // stage A: X rows m0..m0+63, f32 -> bf16
  for (int i = tid; i < 2048; i += 256) {
    const int row = i >> 5, c16 = i & 31;
    BF8U u;
    u.w[0] = 0; u.w[1] = 0; u.w[2] = 0; u.w[3] = 0;
    const int gr = m0 + row;
    if (gr < rows) {
      const int src = idx ? idx[gr] : gr;
      const float* sp = X + (size_t)src * DIM + c16 * 8;
      const float4 x0 = *reinterpret_cast<const float4*>(sp);
      const float4 x1 = *reinterpret_cast<const float4*>(sp + 4);
      u.w[0] = cvt_pk_bf16(x0.x, x0.y);
      u.w[1] = cvt_pk_bf16(x0.z, x0.w);
      u.w[2] = cvt_pk_bf16(x1.x, x1.y);
      u.w[3] = cvt_pk_bf16(x1.z, x1.w);
    }
    *reinterpret_cast<bf16x8*>(As + ((row * 512 + c16 * 16) ^ ((row & 7) << 4))) = u.v;
  }
  // stage B: W rows n0..n0+31
  for (int i = tid; i < 1024; i += 256) {
    const int row = i >> 5, c16 = i & 31;
    const float* sp = W + (size_t)(n0 + row) * DIM + c16 * 8;
    const float4 x0 = *reinterpret_cast<const float4*>(sp);
    const float4 x1 = *reinterpret_cast<const float4*>(sp + 4);
    BF8U u;
    u.w[0] = cvt_pk_bf16(x0.x, x0.y);
    u.w[1] = cvt_pk_bf16(x0.z, x0.w);
    u.w[2] = cvt_pk_bf16(x1.x, x1.y);
    u.w[3] = cvt_pk_bf16(x1.z, x1.w);
    *reinterpret_cast<bf16x8*>(Bs + ((row * 512 + c16 * 16) ^ ((row & 7) << 4))) = u.v;
  }
  __syncthreads();

  f32x4 acc0 = {0.f, 0.f, 0.f, 0.f};
  f32x4 acc1 = {0.f, 0.f, 0.f, 0.f};
#pragma unroll
  for (int kk = 0; kk < 8; kk++) {
    const int arow = w * 16 + t;
    const bf16x8 af = *reinterpret_cast<const bf16x8*>(
        As + ((arow * 512 + (kk * 32 + q * 8) * 2) ^ ((arow & 7) << 4)));
    const bf16x8 bf0 = *reinterpret_cast<const bf16x8*>(
        Bs + ((t * 512 + (kk * 32 + q * 8) * 2) ^ ((t & 7) << 4)));
    const bf16x8 bf1 = *reinterpret_cast<const bf16x8*>(
        Bs + (((16 + t) * 512 + (kk * 32 + q * 8) * 2) ^ (((16 + t) & 7) << 4)));
    acc0 = __builtin_amdgcn_mfma_f32_16x16x32_bf16(af, bf0, acc0, 0, 0, 0);
    acc1 = __builtin_amdgcn_mfma_f32_16x16x32_bf16(af, bf1, acc1, 0, 0, 0);
  }

#pragma unroll
  for (int r = 0; r < 4; r++) {
    const int grow = m0 + w * 16 + q * 4 + r;
    if (grow >= rows) continue;
    const float a0 = acc0[r], a1 = acc1[r];
    const int jj[2] = {n0 + t, n0 + 16 + t};
    const float vv[2] = {(a0 + b[jj[0]]) * scale, (a1 + b[jj[1]]) * scale};
#pragma unroll
    for (int f = 0; f < 2; f++) {
      const int j = jj[f];
      const __hip_bfloat16 hv = __float2bfloat16(vv[f]);
      const int h = j >> 5;
      size_t idxo;
      if (OM == 1) {
        idxo = (((size_t)h * NTT + (grow >> 4)) * 64 + ((j & 31) >> 3) * 16 +
                (grow & 15)) * 8 + (j & 7);
      } else if (OM == 2) {
        idxo = (((size_t)h * 250 + (grow >> 4)) * 64 + ((j & 31) >> 3) * 16 +
                (grow & 15)) * 8 + (j & 7);
      } else {
        const int dh = (j & 31) >> 4, dl = j & 15;
        const int sl = grow & 31;
        const int qv = (sl & 15) >> 2;
        const int ev = (sl & 3) | (((sl >> 4) & 1) << 2);
        idxo = ((((size_t)h * 2 + dh) * NST + (grow >> 5)) * 64 +
                qv * 16 + dl) * 8 + ev;
      }
      outf[idxo] = hv;
    }
  }
}

// ---------------------------------------------------------------------------
// MFMA flash attention (16x16x32), no-max softmax (scores provably bounded),
// permuted-V so P-frag = own QK^T output regs (zero shuffles).
// Block = 4 waves = 2 heads x 2 s-chunks; grid (375, 4).
// ---------------------------------------------------------------------------
template <bool PACKED>
__global__ __launch_bounds__(256, 5) void attn_mfma(
    const __hip_bfloat16* __restrict__ Qf, const __hip_bfloat16* __restrict__ Kf,
    const __hip_bfloat16* __restrict__ Vf, const unsigned int* __restrict__ pc,
    const int* __restrict__ adj, const int* __restrict__ cind,
    const float* __restrict__ edge_emb, const int* __restrict__ tail_idx,
    __hip_bfloat16* __restrict__ Ab)
{
  __shared__ float mg[2][64][12];

  const int tid = threadIdx.x;
  const int w = tid >> 6;
  const int lane = tid & 63;
  const int q = lane >> 4;
  const int t = lane & 15;
  const int hl = w & 1;
  const int cs = w >> 1;
  const int h = blockIdx.y * 2 + hl;
  const int tt = blockIdx.x;
  const int hbase = h * HDIM;

  // lane l holds edge_emb[l][h]
  const float eval = edge_emb[lane * NHEAD + h];

  const bf16x8 qf = *reinterpret_cast<const bf16x8*>(
      Qf + (((size_t)h * NTT + tt) * 64 + lane) * 8);

  const int stBeg = cs ? 63 : 0;
  const int stEnd = cs ? NST : 63;

  const unsigned int* pcp = pc + (size_t)(tt * NST + stBeg) * 128 + q * 16 + t;
  const __hip_bfloat16* kp = Kf + (((size_t)h * 250 + stBeg * 2) * 64 + lane) * 8;
  const __hip_bfloat16* vp = Vf + (((size_t)h * 2 * NST + stBeg) * 64 + lane) * 8;
  const size_t VD = (size_t)NST * 64 * 8;
  const int* crow = cind + (size_t)(tt * 16 + t) * H_N;
  const int* arow = adj + (size_t)(tt * 16 + t) * H_N;

  f32x4 oacc0 = {0.f, 0.f, 0.f, 0.f};
  f32x4 oacc1 = {0.f, 0.f, 0.f, 0.f};
  float Lacc = 0.f;

  unsigned int npc0 = 0, npc1 = 0;
  int4 ncl, nch, nal, nah;
  bf16x8 nk0, nk1, nv0, nv1;
  if (PACKED) {
    npc0 = pcp[0];
    npc1 = pcp[64];
  } else {
    const int sb = stBeg * 32 + q * 4;
    ncl = *reinterpret_cast<const int4*>(crow + sb);
    nch = *reinterpret_cast<const int4*>(crow + sb + 16);
    nal = *reinterpret_cast<const int4*>(arow + sb);
    nah = *reinterpret_cast<const int4*>(arow + sb + 16);
  }
  nk0 = *reinterpret_cast<const bf16x8*>(kp);
  nk1 = *reinterpret_cast<const bf16x8*>(kp + 512);
  nv0 = *reinterpret_cast<const bf16x8*>(vp);
  nv1 = *reinterpret_cast<const bf16x8*>(vp + VD);

  for (int st = stBeg; st < stEnd; ++st) {
    const unsigned int cpc0 = npc0, cpc1 = npc1;
    const int4 ccl = ncl, cch = nch, cal = nal, cah = nah;
    const bf16x8 kf0 = nk0, kf1 = nk1, vf0 = nv0, vf1 = nv1;

    // S^T = K·Q^T : p[r] <-> s_local = 4q + (r&3) + 16*(r>>2), col t
    const f32x4 z = {0.f, 0.f, 0.f, 0.f};
    const f32x4 s_lo = __builtin_amdgcn_mfma_f32_16x16x32_bf16(kf0, qf, z, 0, 0, 0);
    const f32x4 s_hi = __builtin_amdgcn_mfma_f32_16x16x32_bf16(kf1, qf, z, 0, 0, 0);

    if (st + 1 < stEnd) {
      pcp += 128; kp += 1024; vp += 512;
      if (PACKED) {
        npc0 = pcp[0];
        npc1 = pcp[64];
      } else {
        const int sb = (st + 1) * 32 + q * 4;
        ncl = *reinterpret_cast<const int4*>(crow + sb);
        nch = *reinterpret_cast<const int4*>(crow + sb + 16);
        nal = *reinterpret_cast<const int4*>(arow + sb);
        nah = *reinterpret_cast<const int4*>(arow + sb + 16);
      }
      nk0 = *reinterpret_cast<const bf16x8*>(kp);
      nk1 = *reinterpret_cast<const bf16x8*>(kp + 512);
      nv0 = *reinterpret_cast<const bf16x8*>(vp);
      nv1 = *reinterpret_cast<const bf16x8*>(vp + VD);
    }

    // bias + mask + exp (no max subtraction: scores bounded, masked -> 0)
    float p[8];
    if (PACKED) {
#pragma unroll
      for (int r = 0; r < 4; r++) {
        const unsigned b0 = (cpc0 >> (r * 8)) & 0xffu;
        const unsigned b1 = (cpc1 >> (r * 8)) & 0xffu;
        const float e0 = __shfl(eval, (int)(b0 & 63u), 64);
        const float e1 = __shfl(eval, (int)(b1 & 63u), 64);
        p[r] = s_lo[r] + ((b0 & 64u) ? e0 : -1e9f);
        p[r + 4] = s_hi[r] + ((b1 & 64u) ? e1 : -1e9f);
      }
    } else {
      const int cc[8] = {ccl.x, ccl.y, ccl.z, ccl.w, cch.x, cch.y, cch.z, cch.w};
      const int aa[8] = {cal.x, cal.y, cal.z, cal.w, cah.x, cah.y, cah.z, cah.w};
      const float sv[8] = {s_lo[0], s_lo[1], s_lo[2], s_lo[3],
                           s_hi[0], s_hi[1], s_hi[2], s_hi[3]};
#pragma unroll
      for (int r = 0; r < 8; r++) {
        const float e = __shfl(eval, cc[r] & 63, 64);
        p[r] = sv[r] + (aa[r] ? e : -1e9f);
      }
    }
#pragma unroll
    for (int r = 0; r < 8; r++) {
      p[r] = __expf(p[r]);
      Lacc += p[r];
    }

    // P-frag = own regs in order (permuted-V layout): 4 cvt_pk, no shuffles
    BF8U pu;
    pu.w[0] = cvt_pk_bf16(p[0], p[1]);
    pu.w[1] = cvt_pk_bf16(p[2], p[3]);
    pu.w[2] = cvt_pk_bf16(p[4], p[5]);
    pu.w[3] = cvt_pk_bf16(p[6], p[7]);

    // O^T += V^T · P^T
    oacc0 = __builtin_amdgcn_mfma_f32_16x16x32_bf16(vf0, pu.v, oacc0, 0, 0, 0);
    oacc1 = __builtin_amdgcn_mfma_f32_16x16x32_bf16(vf1, pu.v, oacc1, 0, 0, 0);
  }

  // L(t): reduce over the 4 q-groups (lanes t, t+16, t+32, t+48)
  Lacc += __shfl_xor(Lacc, 16, 64);
  Lacc += __shfl_xor(Lacc, 32, 64);

  // merge the two s-chunks (plain sums), epilogue
  if (cs) {
#pragma unroll
    for (int r = 0; r < 4; r++) {
      mg[hl][lane][r] = oacc0[r];
      mg[hl][lane][4 + r] = oacc1[r];
    }
    mg[hl][lane][8] = Lacc;
  }
  __syncthreads();
  if (!cs) {
    const float L = Lacc + mg[hl][lane][8];
    const float inv = 1.f / L;
    float o[8];
#pragma unroll
    for (int r = 0; r < 4; r++) {
      o[r] = (oacc0[r] + mg[hl][lane][r]) * inv;
      o[4 + r] = (oacc1[r] + mg[hl][lane][4 + r]) * inv;
    }
    const int row = tail_idx[tt * 16 + t];
    __hip_bfloat16* dst = Ab + (size_t)row * DIM + hbase + q * 4;
    uint2 w0, w1;
    w0.x = cvt_pk_bf16(o[0], o[1]); w0.y = cvt_pk_bf16(o[2], o[3]);
    w1.x = cvt_pk_bf16(o[4], o[5]); w1.y = cvt_pk_bf16(o[6], o[7]);
    *reinterpret_cast<uint2*>(dst) = w0;
    *reinterpret_cast<uint2*>(dst + 16) = w1;
  }
}

// ---------------------------------------------------------------------------
__global__ __launch_bounds__(64) void copy_head_rows(
    const float* __restrict__ query, const int* __restrict__ head_idx,
    __hip_bfloat16* __restrict__ Ab)
{
  const int row = head_idx[blockIdx.x];
  const int lane = threadIdx.x;
  const float4 v = *reinterpret_cast<const float4*>(
      query + (size_t)row * DIM + lane * 4);
  uint2 o;
  o.x = cvt_pk_bf16(v.x, v.y);
  o.y = cvt_pk_bf16(v.z, v.w);
  *reinterpret_cast<uint2*>(Ab + (size_t)row * DIM + lane * 4) = o;
}

// ---------------------------------------------------------------------------
// O-projection. Grid (8, nRowTiles): consecutive blocks share the A row-tile.
// ---------------------------------------------------------------------------
__global__ __launch_bounds__(256) void oproj_mfma(
    const __hip_bfloat16* __restrict__ Ab, const float* __restrict__ Wo,
    const float* __restrict__ bo, float* __restrict__ out)
{
  __shared__ __align__(16) char As[64 * 512];   // 32 KB
  __shared__ __align__(16) char Bs[32 * 512];   // 16 KB

  const int tid = threadIdx.x;
  const int w = tid >> 6;
  const int lane = tid & 63;
  const int bl = lane & 15;
  const int q = lane >> 4;
  const int n0 = blockIdx.x * 32;
  const int m0 = blockIdx.y * 64;

  for (int i = tid; i < 2048; i += 256) {
    const int row = i >> 5, c16 = i & 31;
    bf16x8 v = {0, 0, 0, 0, 0, 0, 0, 0};
    const int gr = m0 + row;
    if (gr < N_N)
      v = *reinterpret_cast<const bf16x8*>(Ab + (size_t)gr * DIM + c16 * 8);
    *reinterpret_cast<bf16x8*>(As + ((row * 512 + c16 * 16) ^ ((row & 7) << 4))) = v;
  }
  for (int i = tid; i < 1024; i += 256) {
    const int row = i >> 5, c16 = i & 31;
    const float* src = Wo + (size_t)(n0 + row) * DIM + c16 * 8;
    const float4 x0 = *reinterpret_cast<const float4*>(src);
    const float4 x1 = *reinterpret_cast<const float4*>(src + 4);
    BF8U u;
    u.w[0] = cvt_pk_bf16(x0.x, x0.y);
    u.w[1] = cvt_pk_bf16(x0.z, x0.w);
    u.w[2] = cvt_pk_bf16(x1.x, x1.y);
    u.w[3] = cvt_pk_bf16(x1.z, x1.w);
    *reinterpret_cast<bf16x8*>(Bs + ((row * 512 + c16 * 16) ^ ((row & 7) << 4))) = u.v;
  }
  __syncthreads();

  f32x4 acc0 = {0.f, 0.f, 0.f, 0.f};
  f32x4 acc1 = {0.f, 0.f, 0.f, 0.f};
#pragma unroll
  for (int kk = 0; kk < 8; kk++) {
    const int arow = w * 16 + bl;
    const bf16x8 af = *reinterpret_cast<const bf16x8*>(
        As + ((arow * 512 + (kk * 32 + q * 8) * 2) ^ ((arow & 7) << 4)));
    const bf16x8 bf0 = *reinterpret_cast<const bf16x8*>(
        Bs + ((bl * 512 + (kk * 32 + q * 8) * 2) ^ ((bl & 7) << 4)));
    const int brow = 16 + bl;
    const bf16x8 bf1 = *reinterpret_cast<const bf16x8*>(
        Bs + ((brow * 512 + (kk * 32 + q * 8) * 2) ^ ((brow & 7) << 4)));
    acc0 = __builtin_amdgcn_mfma_f32_16x16x32_bf16(af, bf0, acc0, 0, 0, 0);
    acc1 = __builtin_amdgcn_mfma_f32_16x16x32_bf16(af, bf1, acc1, 0, 0, 0);
  }

#pragma unroll
  for (int r = 0; r < 4; r++) {
    const int grow = m0 + w * 16 + q * 4 + r;
    if (grow < N_N) {
      const int j0 = n0 + bl;
      const int j1 = n0 + 16 + bl;
      out[(size_t)grow * DIM + j0] = acc0[r] + bo[j0];
      out[(size_t)grow * DIM + j1] = acc1[r] + bo[j1];
    }
  }
}

// ---------------------------------------------------------------------------
extern "C" void kernel_launch(void* const* d_in, const int* in_sizes, int n_in,
                              void* d_out, int out_size, void* d_ws, size_t ws_size,
                              hipStream_t stream)
{
  const float* query    = (const float*)d_in[0];
  const float* key      = (const float*)d_in[1];
  const float* value    = (const float*)d_in[2];
  const int*   adj      = (const int*)d_in[3];
  const int*   cind     = (const int*)d_in[4];
  const int*   tail_idx = (const int*)d_in[5];
  const int*   head_idx = (const int*)d_in[6];
  const float* Wq = (const float*)d_in[7];
  const float* bq = (const float*)d_in[8];
  const float* Wk = (const float*)d_in[9];
  const float* bk = (const float*)d_in[10];
  const float* Wv = (const float*)d_in[11];
  const float* bv = (const float*)d_in[12];
  const float* Wo = (const float*)d_in[13];
  const float* bo = (const float*)d_in[14];
  const float* edge_emb = (const float*)d_in[15];

  float* out = (float*)d_out;
  char*  ws  = (char*)d_ws;

  // workspace layout (bytes)
  __hip_bfloat16* Ab = (__hip_bfloat16*)ws;                       // 6,144,000
  __hip_bfloat16* Qf = (__hip_bfloat16*)(ws + 6144000);           // 3,072,000
  __hip_bfloat16* Kf = (__hip_bfloat16*)(ws + 9216000);           // 2,048,000
  __hip_bfloat16* Vf = (__hip_bfloat16*)(ws + 11264000);          // 2,048,000
  unsigned int*   pc = (unsigned int*)(ws + 13312000);            // 24,000,000
  const bool packed = ws_size >= (size_t)37312000;

  // rows not covered by tail/head scatter must be zero
  hipMemsetAsync(Ab, 0, (size_t)N_N * DIM * sizeof(__hip_bfloat16), stream);

  if (packed)
    pack_pc<<<dim3((NTT * NST * 128 + 255) / 256), dim3(256), 0, stream>>>(
        adj, cind, pc);

  const dim3 blk(256);
  proj_mfma<1><<<dim3(8, (T_N + 63) / 64), blk, 0, stream>>>(
      query, tail_idx, Wq, bq, Qf, T_N, SCALING);
  proj_mfma<2><<<dim3(8, (H_N + 63) / 64), blk, 0, stream>>>(
      key, head_idx, Wk, bk, Kf, H_N, 1.f);
  proj_mfma<3><<<dim3(8, (H_N + 63) / 64), blk, 0, stream>>>(
      value, head_idx, Wv, bv, Vf, H_N, 1.f);

  if (packed)
    attn_mfma<true><<<dim3(NTT, 4), blk, 0, stream>>>(
        Qf, Kf, Vf, pc, adj, cind, edge_emb, tail_idx, Ab);
  else
    attn_mfma<false><<<dim3(NTT, 4), blk, 0, stream>>>(
        Qf, Kf, Vf, pc, adj, cind, edge_emb, tail_idx, Ab);

  copy_head_rows<<<dim3(H_N), dim3(64), 0, stream>>>(query, head_idx, Ab);

  oproj_mfma<<<dim3(8, (N_N + 63) / 64), blk, 0, stream>>>(
      Ab, Wo, bo, out);
}

// Round 6
// 168.203 us; speedup vs baseline: 48.0770x; 1.0235x over previous
//
#include <hip/hip_runtime.h>
#include <hip/hip_bf16.h>

#define T_N 6000
#define H_N 4000
#define N_N 12000
#define DIM 256
#define NHEAD 8
#define HDIM 32
#define SCALING 0.17677669529663687f   // 32^-0.5
#define LOG2E 1.4426950408889634f
#define NTT 375   // T_N/16 t-tiles
#define NST 125   // H_N/32 s-tiles

typedef __attribute__((ext_vector_type(8))) short bf16x8;
typedef __attribute__((ext_vector_type(4))) float f32x4;

union BF8U { bf16x8 v; unsigned int w[4]; __hip_bfloat16 h[8]; };

static __device__ __forceinline__ unsigned int cvt_pk_bf16(float a, float b) {
  unsigned int r;
  asm("v_cvt_pk_bf16_f32 %0, %1, %2" : "=v"(r) : "v"(a), "v"(b));
  return r;
}

// ---------------------------------------------------------------------------
// Shared MFMA projection body: out = (X[src]·W^T + b)·scale scattered to
// fragment layout (role 1=Qf, 2=Kf, 3=Vf permuted-s). 64x32 tile, K=256
// LDS-staged, XOR-swizzled. bx = rowtile*8 + coltile.
// ---------------------------------------------------------------------------
static __device__ __forceinline__ void proj_body(
    int role, const float* __restrict__ X, const int* __restrict__ idx,
    const float* __restrict__ W, const float* __restrict__ bvec,
    __hip_bfloat16* __restrict__ outf, int rows, float scale, int bx,
    char* As, char* Bs)
{
  const int tid = threadIdx.x;
  const int w = tid >> 6;
  const int lane = tid & 63;
  const int q = lane >> 4;
  const int t = lane & 15;
  const int n0 = (bx & 7) * 32;
  const int m0 = (bx >> 3) * 64;

  for (int i = tid; i < 2048; i += 256) {
    const int row = i >> 5, c16 = i & 31;
    BF8U u;
    u.w[0] = 0; u.w[1] = 0; u.w[2] = 0; u.w[3] = 0;
    const int gr = m0 + row;
    if (gr < rows) {
      const int src = idx ? idx[gr] : gr;
      const float* sp = X + (size_t)src * DIM + c16 * 8;
      const float4 x0 = *reinterpret_cast<const float4*>(sp);
      const float4 x1 = *reinterpret_cast<const float4*>(sp + 4);
      u.w[0] = cvt_pk_bf16(x0.x, x0.y);
      u.w[1] = cvt_pk_bf16(x0.z, x0.w);
      u.w[2] = cvt_pk_bf16(x1.x, x1.y);
      u.w[3] = cvt_pk_bf16(x1.z, x1.w);
    }
    *reinterpret_cast<bf16x8*>(As + ((row * 512 + c16 * 16) ^ ((row & 7) << 4))) = u.v;
  }
  for (int i = tid; i < 1024; i += 256) {
    const int row = i >> 5, c16 = i & 31;
    const float* sp = W + (size_t)(n0 + row) * DIM + c16 * 8;
    const float4 x0 = *reinterpret_cast<const float4*>(sp);
    const float4 x1 = *reinterpret_cast<const float4*>(sp + 4);
    BF8U u;
    u.w[0] = cvt_pk_bf16(x0.x, x0.y);
    u.w[1] = cvt_pk_bf16(x0.z, x0.w);
    u.w[2] = cvt_pk_bf16(x1.x, x1.y);
    u.w[3] = cvt_pk_bf16(x1.z, x1.w);
    *reinterpret_cast<bf16x8*>(Bs + ((row * 512 + c16 * 16) ^ ((row & 7) << 4))) = u.v;
  }
  __syncthreads();

  f32x4 acc0 = {0.f, 0.f, 0.f, 0.f};
  f32x4 acc1 = {0.f, 0.f, 0.f, 0.f};
#pragma unroll
  for (int kk = 0; kk < 8; kk++) {
    const int arow = w * 16 + t;
    const bf16x8 af = *reinterpret_cast<const bf16x8*>(
        As + ((arow * 512 + (kk * 32 + q * 8) * 2) ^ ((arow & 7) << 4)));
    const bf16x8 bf0 = *reinterpret_cast<const bf16x8*>(
        Bs + ((t * 512 + (kk * 32 + q * 8) * 2) ^ ((t & 7) << 4)));
    const bf16x8 bf1 = *reinterpret_cast<const bf16x8*>(
        Bs + (((16 + t) * 512 + (kk * 32 + q * 8) * 2) ^ (((16 + t) & 7) << 4)));
    acc0 = __builtin_amdgcn_mfma_f32_16x16x32_bf16(af, bf0, acc0, 0, 0, 0);
    acc1 = __builtin_amdgcn_mfma_f32_16x16x32_bf16(af, bf1, acc1, 0, 0, 0);
  }

#pragma unroll
  for (int r = 0; r < 4; r++) {
    const int grow = m0 + w * 16 + q * 4 + r;
    if (grow >= rows) continue;
    const float a0 = acc0[r], a1 = acc1[r];
    const int jj[2] = {n0 + t, n0 + 16 + t};
    const float vv[2] = {(a0 + bvec[jj[0]]) * scale, (a1 + bvec[jj[1]]) * scale};
#pragma unroll
    for (int f = 0; f < 2; f++) {
      const int j = jj[f];
      const __hip_bfloat16 hv = __float2bfloat16(vv[f]);
      const int h = j >> 5;
      size_t idxo;
      if (role == 1) {
        idxo = (((size_t)h * NTT + (grow >> 4)) * 64 + ((j & 31) >> 3) * 16 +
                (grow & 15)) * 8 + (j & 7);
      } else if (role == 2) {
        idxo = (((size_t)h * 250 + (grow >> 4)) * 64 + ((j & 31) >> 3) * 16 +
                (grow & 15)) * 8 + (j & 7);
      } else {
        const int dh = (j & 31) >> 4, dl = j & 15;
        const int sl = grow & 31;
        const int qv = (sl & 15) >> 2;
        const int ev = (sl & 3) | (((sl >> 4) & 1) << 2);
        idxo = ((((size_t)h * 2 + dh) * NST + (grow >> 5)) * 64 +
                qv * 16 + dl) * 8 + ev;
      }
      outf[idxo] = hv;
    }
  }
}

// block ranges in the fused pre-kernel
#define NBQ 752        // 8 * 94
#define NBK 504        // 8 * 63
#define NBV 504
#define NBC 1000       // head-row copy, 4 rows/block
#define NBP 23438      // pack: 6,000,000 words / 256

// ---------------------------------------------------------------------------
// Fused pre-pass: projections (MFMA-bound) + head-copy + pack (HBM-bound)
// in one kernel so the two regimes overlap across CUs.
// pack byte = (c<<2) | adj  (addr-ready for ds_bpermute).
// ---------------------------------------------------------------------------
__global__ __launch_bounds__(256) void fused_pre(
    const float* __restrict__ query, const float* __restrict__ key,
    const float* __restrict__ value, const int* __restrict__ adj,
    const int* __restrict__ cind, const int* __restrict__ tail_idx,
    const int* __restrict__ head_idx,
    const float* __restrict__ Wq, const float* __restrict__ bq,
    const float* __restrict__ Wk, const float* __restrict__ bk,
    const float* __restrict__ Wv, const float* __restrict__ bv,
    __hip_bfloat16* __restrict__ Qf, __hip_bfloat16* __restrict__ Kf,
    __hip_bfloat16* __restrict__ Vf, unsigned int* __restrict__ pc,
    __hip_bfloat16* __restrict__ Ab)
{
  __shared__ __align__(16) char As[64 * 512];
  __shared__ __align__(16) char Bs[32 * 512];

  const int bx = blockIdx.x;
  if (bx < NBQ) {
    proj_body(1, query, tail_idx, Wq, bq, Qf, T_N, SCALING * LOG2E, bx, As, Bs);
  } else if (bx < NBQ + NBK) {
    proj_body(2, key, head_idx, Wk, bk, Kf, H_N, 1.f, bx - NBQ, As, Bs);
  } else if (bx < NBQ + NBK + NBV) {
    proj_body(3, value, head_idx, Wv, bv, Vf, H_N, 1.f, bx - NBQ - NBK, As, Bs);
  } else if (bx < NBQ + NBK + NBV + NBC) {
    const int b = bx - NBQ - NBK - NBV;
    const int rr = b * 4 + (threadIdx.x >> 6);
    const int lane = threadIdx.x & 63;
    const int row = head_idx[rr];
    const float4 v = *reinterpret_cast<const float4*>(
        query + (size_t)row * DIM + lane * 4);
    uint2 o;
    o.x = cvt_pk_bf16(v.x, v.y);
    o.y = cvt_pk_bf16(v.z, v.w);
    *reinterpret_cast<uint2*>(Ab + (size_t)row * DIM + lane * 4) = o;
  } else {
    const int i = (bx - NBQ - NBK - NBV - NBC) * 256 + threadIdx.x;
    if (i >= NTT * NST * 128) return;
    const int tl = i & 15;
    const int gi = (i >> 4) & 7;
    const int rem = i >> 7;            // tt*NST + st
    const int st = rem % NST;
    const int tt = rem / NST;
    const int t = tt * 16 + tl;
    const int s0 = st * 32 + gi * 4;
    const int4 c4 = *reinterpret_cast<const int4*>(cind + (size_t)t * H_N + s0);
    const int4 a4 = *reinterpret_cast<const int4*>(adj + (size_t)t * H_N + s0);
    unsigned int w = 0;
    w |= (unsigned)(((c4.x & 63) << 2) | (a4.x ? 1 : 0));
    w |= (unsigned)(((c4.y & 63) << 2) | (a4.y ? 1 : 0)) << 8;
    w |= (unsigned)(((c4.z & 63) << 2) | (a4.z ? 1 : 0)) << 16;
    w |= (unsigned)(((c4.w & 63) << 2) | (a4.w ? 1 : 0)) << 24;
    pc[i] = w;
  }
}

// ---------------------------------------------------------------------------
// MFMA flash attention (16x16x32), exp2 softmax (log2e pre-folded into Q and
// edge table), permuted-V so the P-frag is the QK^T output regs verbatim.
// Grid (375, 8): y = head. Block = 4 waves = 4 s-chunks of ~31 tiles.
// ---------------------------------------------------------------------------
__global__ __launch_bounds__(256, 8) void attn_mfma(
    const __hip_bfloat16* __restrict__ Qf, const __hip_bfloat16* __restrict__ Kf,
    const __hip_bfloat16* __restrict__ Vf, const unsigned int* __restrict__ pc,
    const float* __restrict__ edge_emb, const int* __restrict__ tail_idx,
    __hip_bfloat16* __restrict__ Ab)
{
  __shared__ float mg[3][64][10];

  const int tid = threadIdx.x;
  const int cs = tid >> 6;          // s-chunk
  const int lane = tid & 63;
  const int q = lane >> 4;
  const int t = lane & 15;
  const int h = blockIdx.y;
  const int tt = blockIdx.x;
  const int hbase = h * HDIM;

  // lane l holds edge_emb[l][h] * log2e (table for ds_bpermute)
  const int etab = __float_as_int(edge_emb[lane * NHEAD + h] * LOG2E);

  const bf16x8 qf = *reinterpret_cast<const bf16x8*>(
      Qf + (((size_t)h * NTT + tt) * 64 + lane) * 8);

  const int stBeg = (cs * NST) >> 2;
  const int stEnd = ((cs + 1) * NST) >> 2;

  const unsigned int* pcp = pc + (size_t)(tt * NST + stBeg) * 128 + q * 16 + t;
  const __hip_bfloat16* kp = Kf + (((size_t)h * 250 + stBeg * 2) * 64 + lane) * 8;
  const __hip_bfloat16* vp = Vf + (((size_t)h * 2 * NST + stBeg) * 64 + lane) * 8;
  const size_t VD = (size_t)NST * 64 * 8;

  f32x4 oacc0 = {0.f, 0.f, 0.f, 0.f};
  f32x4 oacc1 = {0.f, 0.f, 0.f, 0.f};
  float Lacc = 0.f;

  unsigned int npc0 = pcp[0], npc1 = pcp[64];
  bf16x8 nk0 = *reinterpret_cast<const bf16x8*>(kp);
  bf16x8 nk1 = *reinterpret_cast<const bf16x8*>(kp + 512);
  bf16x8 nv0 = *reinterpret_cast<const bf16x8*>(vp);
  bf16x8 nv1 = *reinterpret_cast<const bf16x8*>(vp + VD);

  for (int st = stBeg; st < stEnd; ++st) {
    const unsigned int cpc0 = npc0, cpc1 = npc1;
    const bf16x8 kf0 = nk0, kf1 = nk1, vf0 = nv0, vf1 = nv1;

    // S^T = K·Q^T : p[r] <-> s_local = 4q + (r&3) + 16*(r>>2), col t
    const f32x4 z = {0.f, 0.f, 0.f, 0.f};
    const f32x4 s_lo = __builtin_amdgcn_mfma_f32_16x16x32_bf16(kf0, qf, z, 0, 0, 0);
    const f32x4 s_hi = __builtin_amdgcn_mfma_f32_16x16x32_bf16(kf1, qf, z, 0, 0, 0);

    if (st + 1 < stEnd) {
      pcp += 128; kp += 1024; vp += 512;
      npc0 = pcp[0];
      npc1 = pcp[64];
      nk0 = *reinterpret_cast<const bf16x8*>(kp);
      nk1 = *reinterpret_cast<const bf16x8*>(kp + 512);
      nv0 = *reinterpret_cast<const bf16x8*>(vp);
      nv1 = *reinterpret_cast<const bf16x8*>(vp + VD);
    }

    // bias gather (addr pre-shifted in pack) + exp2 softmax, no max needed
    float p[8];
#pragma unroll
    for (int r = 0; r < 4; r++) {
      const unsigned b0 = (cpc0 >> (r * 8)) & 0xffu;
      const unsigned b1 = (cpc1 >> (r * 8)) & 0xffu;
      const int e0 = __builtin_amdgcn_ds_bpermute((int)(b0 & 0xfcu), etab);
      const int e1 = __builtin_amdgcn_ds_bpermute((int)(b1 & 0xfcu), etab);
      const float bb0 = (b0 & 1u) ? __int_as_float(e0) : -1e9f;
      const float bb1 = (b1 & 1u) ? __int_as_float(e1) : -1e9f;
      p[r] = __builtin_amdgcn_exp2f(s_lo[r] + bb0);
      p[r + 4] = __builtin_amdgcn_exp2f(s_hi[r] + bb1);
    }
#pragma unroll
    for (int r = 0; r < 8; r++) Lacc += p[r];

    // P-frag = own regs in order (permuted-V layout)
    BF8U pu;
    pu.w[0] = cvt_pk_bf16(p[0], p[1]);
    pu.w[1] = cvt_pk_bf16(p[2], p[3]);
    pu.w[2] = cvt_pk_bf16(p[4], p[5]);
    pu.w[3] = cvt_pk_bf16(p[6], p[7]);

    oacc0 = __builtin_amdgcn_mfma_f32_16x16x32_bf16(vf0, pu.v, oacc0, 0, 0, 0);
    oacc1 = __builtin_amdgcn_mfma_f32_16x16x32_bf16(vf1, pu.v, oacc1, 0, 0, 0);
  }

  // L(t): reduce over the 4 q-groups
  Lacc += __shfl_xor(Lacc, 16, 64);
  Lacc += __shfl_xor(Lacc, 32, 64);

  // 4-way chunk merge
  if (cs) {
#pragma unroll
    for (int r = 0; r < 4; r++) {
      mg[cs - 1][lane][r] = oacc0[r];
      mg[cs - 1][lane][4 + r] = oacc1[r];
    }
    mg[cs - 1][lane][8] = Lacc;
  }
  __syncthreads();
  if (!cs) {
    float L = Lacc;
    float o[8];
#pragma unroll
    for (int r = 0; r < 8; r++) o[r] = (r < 4) ? oacc0[r] : oacc1[r - 4];
#pragma unroll
    for (int c = 0; c < 3; c++) {
      L += mg[c][lane][8];
#pragma unroll
      for (int r = 0; r < 8; r++) o[r] += mg[c][lane][r];
    }
    const float inv = 1.f / L;
    const int row = tail_idx[tt * 16 + t];
    __hip_bfloat16* dst = Ab + (size_t)row * DIM + hbase + q * 4;
    uint2 w0, w1;
    w0.x = cvt_pk_bf16(o[0] * inv, o[1] * inv);
    w0.y = cvt_pk_bf16(o[2] * inv, o[3] * inv);
    w1.x = cvt_pk_bf16(o[4] * inv, o[5] * inv);
    w1.y = cvt_pk_bf16(o[6] * inv, o[7] * inv);
    *reinterpret_cast<uint2*>(dst) = w0;
    *reinterpret_cast<uint2*>(dst + 16) = w1;
  }
}

// ---------------------------------------------------------------------------
// O-projection: out[r,j] = sum_k Ab[r,k]·Wo[j,k] + bo[j]
// ---------------------------------------------------------------------------
__global__ __launch_bounds__(256) void oproj_mfma(
    const __hip_bfloat16* __restrict__ Ab, const float* __restrict__ Wo,
    const float* __restrict__ bo, float* __restrict__ out)
{
  __shared__ __align__(16) char As[64 * 512];
  __shared__ __align__(16) char Bs[32 * 512];

  const int tid = threadIdx.x;
  const int w = tid >> 6;
  const int lane = tid & 63;
  const int bl = lane & 15;
  const int q = lane >> 4;
  const int n0 = blockIdx.x * 32;
  const int m0 = blockIdx.y * 64;

  for (int i = tid; i < 2048; i += 256) {
    const int row = i >> 5, c16 = i & 31;
    bf16x8 v = {0, 0, 0, 0, 0, 0, 0, 0};
    const int gr = m0 + row;
    if (gr < N_N)
      v = *reinterpret_cast<const bf16x8*>(Ab + (size_t)gr * DIM + c16 * 8);
    *reinterpret_cast<bf16x8*>(As + ((row * 512 + c16 * 16) ^ ((row & 7) << 4))) = v;
  }
  for (int i = tid; i < 1024; i += 256) {
    const int row = i >> 5, c16 = i & 31;
    const float* src = Wo + (size_t)(n0 + row) * DIM + c16 * 8;
    const float4 x0 = *reinterpret_cast<const float4*>(src);
    const float4 x1 = *reinterpret_cast<const float4*>(src + 4);
    BF8U u;
    u.w[0] = cvt_pk_bf16(x0.x, x0.y);
    u.w[1] = cvt_pk_bf16(x0.z, x0.w);
    u.w[2] = cvt_pk_bf16(x1.x, x1.y);
    u.w[3] = cvt_pk_bf16(x1.z, x1.w);
    *reinterpret_cast<bf16x8*>(Bs + ((row * 512 + c16 * 16) ^ ((row & 7) << 4))) = u.v;
  }
  __syncthreads();

  f32x4 acc0 = {0.f, 0.f, 0.f, 0.f};
  f32x4 acc1 = {0.f, 0.f, 0.f, 0.f};
#pragma unroll
  for (int kk = 0; kk < 8; kk++) {
    const int arow = w * 16 + bl;
    const bf16x8 af = *reinterpret_cast<const bf16x8*>(
        As + ((arow * 512 + (kk * 32 + q * 8) * 2) ^ ((arow & 7) << 4)));
    const bf16x8 bf0 = *reinterpret_cast<const bf16x8*>(
        Bs + ((bl * 512 + (kk * 32 + q * 8) * 2) ^ ((bl & 7) << 4)));
    const int brow = 16 + bl;
    const bf16x8 bf1 = *reinterpret_cast<const bf16x8*>(
        Bs + ((brow * 512 + (kk * 32 + q * 8) * 2) ^ ((brow & 7) << 4)));
    acc0 = __builtin_amdgcn_mfma_f32_16x16x32_bf16(af, bf0, acc0, 0, 0, 0);
    acc1 = __builtin_amdgcn_mfma_f32_16x16x32_bf16(af, bf1, acc1, 0, 0, 0);
  }

#pragma unroll
  for (int r = 0; r < 4; r++) {
    const int grow = m0 + w * 16 + q * 4 + r;
    if (grow < N_N) {
      const int j0 = n0 + bl;
      const int j1 = n0 + 16 + bl;
      out[(size_t)grow * DIM + j0] = acc0[r] + bo[j0];
      out[(size_t)grow * DIM + j1] = acc1[r] + bo[j1];
    }
  }
}

// ---------------------------------------------------------------------------
extern "C" void kernel_launch(void* const* d_in, const int* in_sizes, int n_in,
                              void* d_out, int out_size, void* d_ws, size_t ws_size,
                              hipStream_t stream)
{
  const float* query    = (const float*)d_in[0];
  const float* key      = (const float*)d_in[1];
  const float* value    = (const float*)d_in[2];
  const int*   adj      = (const int*)d_in[3];
  const int*   cind     = (const int*)d_in[4];
  const int*   tail_idx = (const int*)d_in[5];
  const int*   head_idx = (const int*)d_in[6];
  const float* Wq = (const float*)d_in[7];
  const float* bq = (const float*)d_in[8];
  const float* Wk = (const float*)d_in[9];
  const float* bk = (const float*)d_in[10];
  const float* Wv = (const float*)d_in[11];
  const float* bv = (const float*)d_in[12];
  const float* Wo = (const float*)d_in[13];
  const float* bo = (const float*)d_in[14];
  const float* edge_emb = (const float*)d_in[15];

  float* out = (float*)d_out;
  char*  ws  = (char*)d_ws;

  __hip_bfloat16* Ab = (__hip_bfloat16*)ws;                       // 6,144,000
  __hip_bfloat16* Qf = (__hip_bfloat16*)(ws + 6144000);           // 3,072,000
  __hip_bfloat16* Kf = (__hip_bfloat16*)(ws + 9216000);           // 2,048,000
  __hip_bfloat16* Vf = (__hip_bfloat16*)(ws + 11264000);          // 2,048,000
  unsigned int*   pc = (unsigned int*)(ws + 13312000);            // 24,000,000

  // rows not covered by tail/head scatter must be zero (ws poisoned 0xAA)
  hipMemsetAsync(Ab, 0, (size_t)N_N * DIM * sizeof(__hip_bfloat16), stream);

  fused_pre<<<dim3(NBQ + NBK + NBV + NBC + NBP), dim3(256), 0, stream>>>(
      query, key, value, adj, cind, tail_idx, head_idx,
      Wq, bq, Wk, bk, Wv, bv, Qf, Kf, Vf, pc, Ab);

  attn_mfma<<<dim3(NTT, NHEAD), dim3(256), 0, stream>>>(
      Qf, Kf, Vf, pc, edge_emb, tail_idx, Ab);

  oproj_mfma<<<dim3(8, (N_N + 63) / 64), dim3(256), 0, stream>>>(
      Ab, Wo, bo, out);
}